// Round 4
// baseline (522.866 us; speedup 1.0000x reference)
//
#include <hip/hip_runtime.h>

// GCN 2-layer forward on MI355X.
// Pipeline per call (all on `stream`, graph-capture safe):
//   memset(cnt,cursor) -> count(dst) -> scan+dinv -> scatter(CSR by dst)
//   -> gemm(x,W1)->ws.buf -> agg+bias+relu -> d_out
//   -> gemm(d_out,W2)->ws.buf -> agg+bias+relu -> d_out
// NOTE: harness stages integer inputs as int32 -> edge_index is const int*.

#define NNODES 50000

// ---- CSR build -------------------------------------------------------------

__global__ void count_kernel(const int* __restrict__ dst, int* __restrict__ cnt, int E) {
    int e = blockIdx.x * blockDim.x + threadIdx.x;
    if (e < E) atomicAdd(&cnt[dst[e]], 1);
}

// single-block scan over N counts -> exclusive row_start, plus dinv = rsqrt(deg+1)
__global__ void scan_kernel(const int* __restrict__ cnt, int* __restrict__ row_start,
                            float* __restrict__ dinv, int N) {
    __shared__ int part[1024];
    int t = threadIdx.x;
    int chunk = (N + 1023) >> 10;
    int beg = t * chunk;
    int end = min(N, beg + chunk);
    int sum = 0;
    for (int i = beg; i < end; ++i) sum += cnt[i];
    part[t] = sum;
    __syncthreads();
    // Hillis-Steele inclusive scan over 1024 partials
    for (int off = 1; off < 1024; off <<= 1) {
        int v = (t >= off) ? part[t - off] : 0;
        __syncthreads();
        part[t] += v;
        __syncthreads();
    }
    int run = (t == 0) ? 0 : part[t - 1];
    for (int i = beg; i < end; ++i) {
        row_start[i] = run;
        int c = cnt[i];
        dinv[i] = rsqrtf((float)(c + 1));  // +1 self-loop; deg>=1 always
        run += c;
    }
    if (beg < N && end == N) row_start[N] = run;
}

__global__ void scatter_kernel(const int* __restrict__ src, const int* __restrict__ dst,
                               const int* __restrict__ row_start, int* __restrict__ cursor,
                               int* __restrict__ esrc, int E) {
    int e = blockIdx.x * blockDim.x + threadIdx.x;
    if (e < E) {
        int d = dst[e];
        int p = row_start[d] + atomicAdd(&cursor[d], 1);
        esrc[p] = src[e];
    }
}

// ---- GEMM: H[M x 128] = A[M x K] @ W[K x 128] ------------------------------
// Block: 256 threads computes 32 rows x 128 cols; thread: 4x4 micro-tile.

__global__ __launch_bounds__(256) void gemm_kernel(const float* __restrict__ A,
                                                   const float* __restrict__ W,
                                                   float* __restrict__ H, int M, int K) {
    constexpr int NOUT = 128;
    __shared__ float sA[32][33];      // +1 pad
    __shared__ float sW[32][NOUT];
    int row0 = blockIdx.x * 32;
    int t  = threadIdx.x;
    int tx = t & 31;   // col group: cols tx*4 .. tx*4+3
    int ty = t >> 5;   // row group: rows ty*4 .. ty*4+3
    float acc[4][4] = {};
    for (int k0 = 0; k0 < K; k0 += 32) {
        int kc = K - k0; if (kc > 32) kc = 32;
        for (int i = t; i < 32 * 32; i += 256) {
            int r = i >> 5, c = i & 31;
            int gr = row0 + r;
            sA[r][c] = (c < kc && gr < M) ? A[(size_t)gr * K + k0 + c] : 0.f;
        }
        for (int i = t; i < 32 * NOUT; i += 256) {
            int r = i >> 7, c = i & 127;
            sW[r][c] = (r < kc) ? W[(size_t)(k0 + r) * NOUT + c] : 0.f;
        }
        __syncthreads();
#pragma unroll
        for (int kk = 0; kk < 32; ++kk) {
            float4 b = *reinterpret_cast<const float4*>(&sW[kk][tx * 4]);
            float a0 = sA[ty * 4 + 0][kk];
            float a1 = sA[ty * 4 + 1][kk];
            float a2 = sA[ty * 4 + 2][kk];
            float a3 = sA[ty * 4 + 3][kk];
            acc[0][0] = fmaf(a0, b.x, acc[0][0]); acc[0][1] = fmaf(a0, b.y, acc[0][1]);
            acc[0][2] = fmaf(a0, b.z, acc[0][2]); acc[0][3] = fmaf(a0, b.w, acc[0][3]);
            acc[1][0] = fmaf(a1, b.x, acc[1][0]); acc[1][1] = fmaf(a1, b.y, acc[1][1]);
            acc[1][2] = fmaf(a1, b.z, acc[1][2]); acc[1][3] = fmaf(a1, b.w, acc[1][3]);
            acc[2][0] = fmaf(a2, b.x, acc[2][0]); acc[2][1] = fmaf(a2, b.y, acc[2][1]);
            acc[2][2] = fmaf(a2, b.z, acc[2][2]); acc[2][3] = fmaf(a2, b.w, acc[2][3]);
            acc[3][0] = fmaf(a3, b.x, acc[3][0]); acc[3][1] = fmaf(a3, b.y, acc[3][1]);
            acc[3][2] = fmaf(a3, b.z, acc[3][2]); acc[3][3] = fmaf(a3, b.w, acc[3][3]);
        }
        __syncthreads();
    }
#pragma unroll
    for (int i = 0; i < 4; ++i) {
        int gr = row0 + ty * 4 + i;
        if (gr < M) {
            *reinterpret_cast<float4*>(&H[(size_t)gr * NOUT + tx * 4]) =
                make_float4(acc[i][0], acc[i][1], acc[i][2], acc[i][3]);
        }
    }
}

// ---- Aggregation: out[i,f] = relu(dinv[i]*sum_e dinv[s]*H[s,f] + dinv[i]^2*H[i,f] + b[f])
// One 128-thread block per node; thread f owns feature f. Edge list staged in LDS.

__global__ __launch_bounds__(128) void agg_kernel(const float* __restrict__ H,
                                                  const int* __restrict__ row_start,
                                                  const int* __restrict__ esrc,
                                                  const float* __restrict__ dinv,
                                                  const float* __restrict__ bias,
                                                  float* __restrict__ out, int N) {
    constexpr int F = 128;
    __shared__ int   s_idx[128];
    __shared__ float s_w[128];
    int i = blockIdx.x;
    int f = threadIdx.x;
    int beg = row_start[i];
    int end = row_start[i + 1];
    float acc = 0.f;
    for (int base = beg; base < end; base += 128) {
        int m = end - base; if (m > 128) m = 128;
        __syncthreads();
        if (f < m) {
            int s = esrc[base + f];
            s_idx[f] = s;
            s_w[f]   = dinv[s];
        }
        __syncthreads();
        for (int j = 0; j < m; ++j)
            acc = fmaf(s_w[j], H[(size_t)s_idx[j] * F + f], acc);
    }
    float di = dinv[i];
    float hv = H[(size_t)i * F + f];
    float v  = fmaf(di, acc, fmaf(di * di, hv, bias[f]));
    out[(size_t)i * F + f] = fmaxf(v, 0.f);
}

// ---- launch ----------------------------------------------------------------

extern "C" void kernel_launch(void* const* d_in, const int* in_sizes, int n_in,
                              void* d_out, int out_size, void* d_ws, size_t ws_size,
                              hipStream_t stream) {
    const float* x  = (const float*)d_in[0];
    const int*   ei = (const int*)d_in[1];     // int32 per harness staging
    const float* W1 = (const float*)d_in[2];
    const float* b1 = (const float*)d_in[3];
    const float* W2 = (const float*)d_in[4];
    const float* b2 = (const float*)d_in[5];

    const int N   = NNODES;
    const int E   = in_sizes[1] / 2;       // 800000
    const int K1  = in_sizes[0] / N;       // 130
    const int HID = in_sizes[3];           // 128

    const int* src = ei;
    const int* dst = ei + E;

    // workspace layout (all 16B-aligned by construction)
    int*   cnt       = (int*)d_ws;              // N
    int*   cursor    = cnt + N;                 // N
    int*   row_start = cursor + N;              // N+1 (padded to N+4)
    float* dinv      = (float*)(row_start + N + 4);
    int*   esrc      = (int*)(dinv + N);        // E
    float* buf       = (float*)(esrc + E);      // N*HID (scratch GEMM output)
    float* outf      = (float*)d_out;           // N*HID (also used as intermediate)

    hipMemsetAsync(cnt, 0, sizeof(int) * 2 * (size_t)N, stream);  // cnt + cursor

    count_kernel<<<(E + 255) / 256, 256, 0, stream>>>(dst, cnt, E);
    scan_kernel<<<1, 1024, 0, stream>>>(cnt, row_start, dinv, N);
    scatter_kernel<<<(E + 255) / 256, 256, 0, stream>>>(src, dst, row_start, cursor, esrc, E);

    // layer 1: gemm -> buf, agg -> d_out
    gemm_kernel<<<(N + 31) / 32, 256, 0, stream>>>(x, W1, buf, N, K1);
    agg_kernel<<<N, 128, 0, stream>>>(buf, row_start, esrc, dinv, b1, outf, N);
    // layer 2: gemm(d_out) -> buf, agg -> d_out
    gemm_kernel<<<(N + 31) / 32, 256, 0, stream>>>(outf, W2, buf, N, HID);
    agg_kernel<<<N, 128, 0, stream>>>(buf, row_start, esrc, dinv, b2, outf, N);
}

// Round 5
// 427.800 us; speedup vs baseline: 1.2222x; 1.2222x over previous
//
#include <hip/hip_runtime.h>

// GCN 2-layer forward on MI355X.
// Pipeline per call (all on `stream`, graph-capture safe):
//   memset(cnt,cursor) -> count(dst) -> 3-kernel decoupled scan (+dinv)
//   -> scatter(CSR by dst)
//   -> gemm(x,W1)->ws.buf -> agg+bias+relu -> d_out
//   -> gemm(d_out,W2)->ws.buf -> agg+bias+relu -> d_out
// NOTE: harness stages integer inputs as int32 -> edge_index is const int*.
// R4: replaced single-block scan_kernel (110 us, 0.14% occupancy) with
//     3-kernel parallel scan (~10 us).

#define NNODES 50000

// ---- CSR build -------------------------------------------------------------

__global__ void count_kernel(const int* __restrict__ dst, int* __restrict__ cnt, int E) {
    int e = blockIdx.x * blockDim.x + threadIdx.x;
    if (e < E) atomicAdd(&cnt[dst[e]], 1);
}

// A: per-block (256-elem chunk) sum of cnt -> bsum[b]
__global__ __launch_bounds__(256) void scan_blocksum(const int* __restrict__ cnt,
                                                     int* __restrict__ bsum, int N) {
    __shared__ int ws[4];
    int i = blockIdx.x * 256 + threadIdx.x;
    int v = (i < N) ? cnt[i] : 0;
#pragma unroll
    for (int off = 1; off < 64; off <<= 1) v += __shfl_xor(v, off);
    int lane = threadIdx.x & 63, w = threadIdx.x >> 6;
    if (lane == 0) ws[w] = v;
    __syncthreads();
    if (threadIdx.x == 0) bsum[blockIdx.x] = ws[0] + ws[1] + ws[2] + ws[3];
}

// B: single block scans NB (<=256) partials -> exclusive boff; writes row_start[N]
__global__ __launch_bounds__(256) void scan_partials(const int* __restrict__ bsum,
                                                     int* __restrict__ boff,
                                                     int* __restrict__ row_start,
                                                     int NB, int N) {
    __shared__ int ws[4];
    int t = threadIdx.x;
    int v = (t < NB) ? bsum[t] : 0;
    int lane = t & 63, w = t >> 6;
    int inc = v;
#pragma unroll
    for (int off = 1; off < 64; off <<= 1) {
        int n = __shfl_up(inc, off);
        if (lane >= off) inc += n;
    }
    if (lane == 63) ws[w] = inc;
    __syncthreads();
    int woff = 0;
    for (int k = 0; k < w; ++k) woff += ws[k];
    int excl = woff + inc - v;
    if (t < NB) boff[t] = excl;
    if (t == NB - 1) row_start[N] = excl + v;  // grand total = E
}

// C: per-block exclusive scan of its chunk + boff[b] -> row_start; also dinv
__global__ __launch_bounds__(256) void scan_final(const int* __restrict__ cnt,
                                                  const int* __restrict__ boff,
                                                  int* __restrict__ row_start,
                                                  float* __restrict__ dinv, int N) {
    __shared__ int ws[4];
    int i = blockIdx.x * 256 + threadIdx.x;
    int v = (i < N) ? cnt[i] : 0;
    int lane = threadIdx.x & 63, w = threadIdx.x >> 6;
    int inc = v;
#pragma unroll
    for (int off = 1; off < 64; off <<= 1) {
        int n = __shfl_up(inc, off);
        if (lane >= off) inc += n;
    }
    if (lane == 63) ws[w] = inc;
    __syncthreads();
    int woff = 0;
    for (int k = 0; k < w; ++k) woff += ws[k];
    if (i < N) {
        row_start[i] = boff[blockIdx.x] + woff + inc - v;
        dinv[i] = rsqrtf((float)(v + 1));  // +1 self-loop; deg>=1 always
    }
}

__global__ void scatter_kernel(const int* __restrict__ src, const int* __restrict__ dst,
                               const int* __restrict__ row_start, int* __restrict__ cursor,
                               int* __restrict__ esrc, int E) {
    int e = blockIdx.x * blockDim.x + threadIdx.x;
    if (e < E) {
        int d = dst[e];
        int p = row_start[d] + atomicAdd(&cursor[d], 1);
        esrc[p] = src[e];
    }
}

// ---- GEMM: H[M x 128] = A[M x K] @ W[K x 128] ------------------------------
// Block: 256 threads computes 32 rows x 128 cols; thread: 4x4 micro-tile.

__global__ __launch_bounds__(256) void gemm_kernel(const float* __restrict__ A,
                                                   const float* __restrict__ W,
                                                   float* __restrict__ H, int M, int K) {
    constexpr int NOUT = 128;
    __shared__ float sA[32][33];      // +1 pad
    __shared__ float sW[32][NOUT];
    int row0 = blockIdx.x * 32;
    int t  = threadIdx.x;
    int tx = t & 31;   // col group: cols tx*4 .. tx*4+3
    int ty = t >> 5;   // row group: rows ty*4 .. ty*4+3
    float acc[4][4] = {};
    for (int k0 = 0; k0 < K; k0 += 32) {
        int kc = K - k0; if (kc > 32) kc = 32;
        for (int i = t; i < 32 * 32; i += 256) {
            int r = i >> 5, c = i & 31;
            int gr = row0 + r;
            sA[r][c] = (c < kc && gr < M) ? A[(size_t)gr * K + k0 + c] : 0.f;
        }
        for (int i = t; i < 32 * NOUT; i += 256) {
            int r = i >> 7, c = i & 127;
            sW[r][c] = (r < kc) ? W[(size_t)(k0 + r) * NOUT + c] : 0.f;
        }
        __syncthreads();
#pragma unroll
        for (int kk = 0; kk < 32; ++kk) {
            float4 b = *reinterpret_cast<const float4*>(&sW[kk][tx * 4]);
            float a0 = sA[ty * 4 + 0][kk];
            float a1 = sA[ty * 4 + 1][kk];
            float a2 = sA[ty * 4 + 2][kk];
            float a3 = sA[ty * 4 + 3][kk];
            acc[0][0] = fmaf(a0, b.x, acc[0][0]); acc[0][1] = fmaf(a0, b.y, acc[0][1]);
            acc[0][2] = fmaf(a0, b.z, acc[0][2]); acc[0][3] = fmaf(a0, b.w, acc[0][3]);
            acc[1][0] = fmaf(a1, b.x, acc[1][0]); acc[1][1] = fmaf(a1, b.y, acc[1][1]);
            acc[1][2] = fmaf(a1, b.z, acc[1][2]); acc[1][3] = fmaf(a1, b.w, acc[1][3]);
            acc[2][0] = fmaf(a2, b.x, acc[2][0]); acc[2][1] = fmaf(a2, b.y, acc[2][1]);
            acc[2][2] = fmaf(a2, b.z, acc[2][2]); acc[2][3] = fmaf(a2, b.w, acc[2][3]);
            acc[3][0] = fmaf(a3, b.x, acc[3][0]); acc[3][1] = fmaf(a3, b.y, acc[3][1]);
            acc[3][2] = fmaf(a3, b.z, acc[3][2]); acc[3][3] = fmaf(a3, b.w, acc[3][3]);
        }
        __syncthreads();
    }
#pragma unroll
    for (int i = 0; i < 4; ++i) {
        int gr = row0 + ty * 4 + i;
        if (gr < M) {
            *reinterpret_cast<float4*>(&H[(size_t)gr * NOUT + tx * 4]) =
                make_float4(acc[i][0], acc[i][1], acc[i][2], acc[i][3]);
        }
    }
}

// ---- Aggregation: out[i,f] = relu(dinv[i]*sum_e dinv[s]*H[s,f] + dinv[i]^2*H[i,f] + b[f])
// One 128-thread block per node; thread f owns feature f. Edge list staged in LDS.

__global__ __launch_bounds__(128) void agg_kernel(const float* __restrict__ H,
                                                  const int* __restrict__ row_start,
                                                  const int* __restrict__ esrc,
                                                  const float* __restrict__ dinv,
                                                  const float* __restrict__ bias,
                                                  float* __restrict__ out, int N) {
    constexpr int F = 128;
    __shared__ int   s_idx[128];
    __shared__ float s_w[128];
    int i = blockIdx.x;
    int f = threadIdx.x;
    int beg = row_start[i];
    int end = row_start[i + 1];
    float acc = 0.f;
    for (int base = beg; base < end; base += 128) {
        int m = end - base; if (m > 128) m = 128;
        __syncthreads();
        if (f < m) {
            int s = esrc[base + f];
            s_idx[f] = s;
            s_w[f]   = dinv[s];
        }
        __syncthreads();
        for (int j = 0; j < m; ++j)
            acc = fmaf(s_w[j], H[(size_t)s_idx[j] * F + f], acc);
    }
    float di = dinv[i];
    float hv = H[(size_t)i * F + f];
    float v  = fmaf(di, acc, fmaf(di * di, hv, bias[f]));
    out[(size_t)i * F + f] = fmaxf(v, 0.f);
}

// ---- launch ----------------------------------------------------------------

extern "C" void kernel_launch(void* const* d_in, const int* in_sizes, int n_in,
                              void* d_out, int out_size, void* d_ws, size_t ws_size,
                              hipStream_t stream) {
    const float* x  = (const float*)d_in[0];
    const int*   ei = (const int*)d_in[1];     // int32 per harness staging
    const float* W1 = (const float*)d_in[2];
    const float* b1 = (const float*)d_in[3];
    const float* W2 = (const float*)d_in[4];
    const float* b2 = (const float*)d_in[5];

    const int N   = NNODES;
    const int E   = in_sizes[1] / 2;       // 800000
    const int K1  = in_sizes[0] / N;       // 130
    const int HID = in_sizes[3];           // 128
    const int NB  = (N + 255) / 256;       // scan blocks (196)

    const int* src = ei;
    const int* dst = ei + E;

    // workspace layout (all 16B-aligned by construction)
    int*   cnt       = (int*)d_ws;              // N
    int*   cursor    = cnt + N;                 // N
    int*   row_start = cursor + N;              // N+1 (padded to N+4)
    float* dinv      = (float*)(row_start + N + 4);
    int*   bsum      = (int*)(dinv + N);        // NB (pad 256)
    int*   boff      = bsum + 256;              // NB (pad 256)
    int*   esrc      = boff + 256;              // E
    float* buf       = (float*)(esrc + E);      // N*HID (scratch GEMM output)
    float* outf      = (float*)d_out;           // N*HID (also used as intermediate)

    hipMemsetAsync(cnt, 0, sizeof(int) * 2 * (size_t)N, stream);  // cnt + cursor

    count_kernel<<<(E + 255) / 256, 256, 0, stream>>>(dst, cnt, E);
    scan_blocksum<<<NB, 256, 0, stream>>>(cnt, bsum, N);
    scan_partials<<<1, 256, 0, stream>>>(bsum, boff, row_start, NB, N);
    scan_final<<<NB, 256, 0, stream>>>(cnt, boff, row_start, dinv, N);
    scatter_kernel<<<(E + 255) / 256, 256, 0, stream>>>(src, dst, row_start, cursor, esrc, E);

    // layer 1: gemm -> buf, agg -> d_out
    gemm_kernel<<<(N + 31) / 32, 256, 0, stream>>>(x, W1, buf, N, K1);
    agg_kernel<<<N, 128, 0, stream>>>(buf, row_start, esrc, dinv, b1, outf, N);
    // layer 2: gemm(d_out) -> buf, agg -> d_out
    gemm_kernel<<<(N + 31) / 32, 256, 0, stream>>>(outf, W2, buf, N, HID);
    agg_kernel<<<N, 128, 0, stream>>>(buf, row_start, esrc, dinv, b2, outf, N);
}

// Round 6
// 385.731 us; speedup vs baseline: 1.3555x; 1.1091x over previous
//
#include <hip/hip_runtime.h>

// GCN 2-layer forward on MI355X.
// Pipeline per call (all on `stream`, graph-capture safe):
//   memset(cnt,cursor) -> count(dst) -> 3-kernel decoupled scan (+dinv)
//   -> scatter(CSR by dst)
//   -> gemm(x,W1)->ws.buf -> agg+bias+relu -> d_out
//   -> gemm(d_out,W2)->ws.buf -> agg+bias+relu -> d_out
// NOTE: harness stages integer inputs as int32 -> edge_index is const int*.
// R4: parallel 3-kernel scan (110us -> ~5us).
// R5: GEMM rewrite: 128x128 tile, 8x8 micro-tile, 2 FLOP/LDS-byte, split-col
//     B reads (2-way bank alias = free). Was 22 TF (VALUBusy 30%); target >60 TF.

#define NNODES 50000

// ---- CSR build -------------------------------------------------------------

__global__ void count_kernel(const int* __restrict__ dst, int* __restrict__ cnt, int E) {
    int e = blockIdx.x * blockDim.x + threadIdx.x;
    if (e < E) atomicAdd(&cnt[dst[e]], 1);
}

// A: per-block (256-elem chunk) sum of cnt -> bsum[b]
__global__ __launch_bounds__(256) void scan_blocksum(const int* __restrict__ cnt,
                                                     int* __restrict__ bsum, int N) {
    __shared__ int ws[4];
    int i = blockIdx.x * 256 + threadIdx.x;
    int v = (i < N) ? cnt[i] : 0;
#pragma unroll
    for (int off = 1; off < 64; off <<= 1) v += __shfl_xor(v, off);
    int lane = threadIdx.x & 63, w = threadIdx.x >> 6;
    if (lane == 0) ws[w] = v;
    __syncthreads();
    if (threadIdx.x == 0) bsum[blockIdx.x] = ws[0] + ws[1] + ws[2] + ws[3];
}

// B: single block scans NB (<=256) partials -> exclusive boff; writes row_start[N]
__global__ __launch_bounds__(256) void scan_partials(const int* __restrict__ bsum,
                                                     int* __restrict__ boff,
                                                     int* __restrict__ row_start,
                                                     int NB, int N) {
    __shared__ int ws[4];
    int t = threadIdx.x;
    int v = (t < NB) ? bsum[t] : 0;
    int lane = t & 63, w = t >> 6;
    int inc = v;
#pragma unroll
    for (int off = 1; off < 64; off <<= 1) {
        int n = __shfl_up(inc, off);
        if (lane >= off) inc += n;
    }
    if (lane == 63) ws[w] = inc;
    __syncthreads();
    int woff = 0;
    for (int k = 0; k < w; ++k) woff += ws[k];
    int excl = woff + inc - v;
    if (t < NB) boff[t] = excl;
    if (t == NB - 1) row_start[N] = excl + v;  // grand total = E
}

// C: per-block exclusive scan of its chunk + boff[b] -> row_start; also dinv
__global__ __launch_bounds__(256) void scan_final(const int* __restrict__ cnt,
                                                  const int* __restrict__ boff,
                                                  int* __restrict__ row_start,
                                                  float* __restrict__ dinv, int N) {
    __shared__ int ws[4];
    int i = blockIdx.x * 256 + threadIdx.x;
    int v = (i < N) ? cnt[i] : 0;
    int lane = threadIdx.x & 63, w = threadIdx.x >> 6;
    int inc = v;
#pragma unroll
    for (int off = 1; off < 64; off <<= 1) {
        int n = __shfl_up(inc, off);
        if (lane >= off) inc += n;
    }
    if (lane == 63) ws[w] = inc;
    __syncthreads();
    int woff = 0;
    for (int k = 0; k < w; ++k) woff += ws[k];
    if (i < N) {
        row_start[i] = boff[blockIdx.x] + woff + inc - v;
        dinv[i] = rsqrtf((float)(v + 1));  // +1 self-loop; deg>=1 always
    }
}

__global__ void scatter_kernel(const int* __restrict__ src, const int* __restrict__ dst,
                               const int* __restrict__ row_start, int* __restrict__ cursor,
                               int* __restrict__ esrc, int E) {
    int e = blockIdx.x * blockDim.x + threadIdx.x;
    if (e < E) {
        int d = dst[e];
        int p = row_start[d] + atomicAdd(&cursor[d], 1);
        esrc[p] = src[e];
    }
}

// ---- GEMM: H[M x 128] = A[M x K] @ W[K x 128] ------------------------------
// 128x128 block tile, 256 threads, 8x8 micro-tile. A tile row-major stride 34
// (broadcast scalar reads, <=2-way alias); B cols split {tx*4, 64+tx*4} so each
// ds_read_b128 spans 256B (2-way alias = free). VALU-bound by design.

__global__ __launch_bounds__(256) void gemm_kernel(const float* __restrict__ A,
                                                   const float* __restrict__ W,
                                                   float* __restrict__ H, int M, int K) {
    constexpr int BM = 128, BN = 128, BK = 32, LDA = BK + 2;  // 34
    __shared__ float sA[BM * LDA];
    __shared__ float sW[BK][BN];
    int t = threadIdx.x;
    int row0 = blockIdx.x * BM;
    int tx = t & 15;   // cols tx*4..+3 and 64+tx*4..+3
    int ty = t >> 4;   // rows ty*8..+7
    float acc[8][8] = {};

    for (int k0 = 0; k0 < K; k0 += BK) {
        // stage A: BM x BK as float2 (rows 8B-aligned: K is even)
#pragma unroll
        for (int j = 0; j < 8; ++j) {
            int s  = t + 256 * j;      // 0..2047
            int r  = s >> 4;           // 0..127
            int c2 = s & 15;           // float2 slot in row
            int gr = row0 + r;
            int gk = k0 + c2 * 2;
            float2 v = make_float2(0.f, 0.f);
            if (gr < M) {
                if (gk + 1 < K)      v = *reinterpret_cast<const float2*>(&A[(size_t)gr * K + gk]);
                else if (gk < K)     v.x = A[(size_t)gr * K + gk];
            }
            *reinterpret_cast<float2*>(&sA[r * LDA + c2 * 2]) = v;
        }
        // stage W: BK x BN as float4
#pragma unroll
        for (int j = 0; j < 4; ++j) {
            int s  = t + 256 * j;      // 0..1023
            int r  = s >> 5;           // 0..31
            int c4 = s & 31;
            int gk = k0 + r;
            float4 v = make_float4(0.f, 0.f, 0.f, 0.f);
            if (gk < K) v = *reinterpret_cast<const float4*>(&W[(size_t)gk * BN + c4 * 4]);
            *reinterpret_cast<float4*>(&sW[r][c4 * 4]) = v;
        }
        __syncthreads();
#pragma unroll 4
        for (int kk = 0; kk < BK; ++kk) {
            float4 b0 = *reinterpret_cast<const float4*>(&sW[kk][tx * 4]);
            float4 b1 = *reinterpret_cast<const float4*>(&sW[kk][64 + tx * 4]);
            float a[8];
#pragma unroll
            for (int i = 0; i < 8; ++i) a[i] = sA[(ty * 8 + i) * LDA + kk];
#pragma unroll
            for (int i = 0; i < 8; ++i) {
                acc[i][0] = fmaf(a[i], b0.x, acc[i][0]);
                acc[i][1] = fmaf(a[i], b0.y, acc[i][1]);
                acc[i][2] = fmaf(a[i], b0.z, acc[i][2]);
                acc[i][3] = fmaf(a[i], b0.w, acc[i][3]);
                acc[i][4] = fmaf(a[i], b1.x, acc[i][4]);
                acc[i][5] = fmaf(a[i], b1.y, acc[i][5]);
                acc[i][6] = fmaf(a[i], b1.z, acc[i][6]);
                acc[i][7] = fmaf(a[i], b1.w, acc[i][7]);
            }
        }
        __syncthreads();
    }
#pragma unroll
    for (int i = 0; i < 8; ++i) {
        int gr = row0 + ty * 8 + i;
        if (gr < M) {
            *reinterpret_cast<float4*>(&H[(size_t)gr * BN + tx * 4]) =
                make_float4(acc[i][0], acc[i][1], acc[i][2], acc[i][3]);
            *reinterpret_cast<float4*>(&H[(size_t)gr * BN + 64 + tx * 4]) =
                make_float4(acc[i][4], acc[i][5], acc[i][6], acc[i][7]);
        }
    }
}

// ---- Aggregation: out[i,f] = relu(dinv[i]*sum_e dinv[s]*H[s,f] + dinv[i]^2*H[i,f] + b[f])
// One 128-thread block per node; thread f owns feature f. Edge list staged in LDS.

__global__ __launch_bounds__(128) void agg_kernel(const float* __restrict__ H,
                                                  const int* __restrict__ row_start,
                                                  const int* __restrict__ esrc,
                                                  const float* __restrict__ dinv,
                                                  const float* __restrict__ bias,
                                                  float* __restrict__ out, int N) {
    constexpr int F = 128;
    __shared__ int   s_idx[128];
    __shared__ float s_w[128];
    int i = blockIdx.x;
    int f = threadIdx.x;
    int beg = row_start[i];
    int end = row_start[i + 1];
    float acc = 0.f;
    for (int base = beg; base < end; base += 128) {
        int m = end - base; if (m > 128) m = 128;
        __syncthreads();
        if (f < m) {
            int s = esrc[base + f];
            s_idx[f] = s;
            s_w[f]   = dinv[s];
        }
        __syncthreads();
        for (int j = 0; j < m; ++j)
            acc = fmaf(s_w[j], H[(size_t)s_idx[j] * F + f], acc);
    }
    float di = dinv[i];
    float hv = H[(size_t)i * F + f];
    float v  = fmaf(di, acc, fmaf(di * di, hv, bias[f]));
    out[(size_t)i * F + f] = fmaxf(v, 0.f);
}

// ---- launch ----------------------------------------------------------------

extern "C" void kernel_launch(void* const* d_in, const int* in_sizes, int n_in,
                              void* d_out, int out_size, void* d_ws, size_t ws_size,
                              hipStream_t stream) {
    const float* x  = (const float*)d_in[0];
    const int*   ei = (const int*)d_in[1];     // int32 per harness staging
    const float* W1 = (const float*)d_in[2];
    const float* b1 = (const float*)d_in[3];
    const float* W2 = (const float*)d_in[4];
    const float* b2 = (const float*)d_in[5];

    const int N   = NNODES;
    const int E   = in_sizes[1] / 2;       // 800000
    const int K1  = in_sizes[0] / N;       // 130
    const int HID = in_sizes[3];           // 128
    const int NB  = (N + 255) / 256;       // scan blocks (196)

    const int* src = ei;
    const int* dst = ei + E;

    // workspace layout (all 16B-aligned by construction)
    int*   cnt       = (int*)d_ws;              // N
    int*   cursor    = cnt + N;                 // N
    int*   row_start = cursor + N;              // N+1 (padded to N+4)
    float* dinv      = (float*)(row_start + N + 4);
    int*   bsum      = (int*)(dinv + N);        // NB (pad 256)
    int*   boff      = bsum + 256;              // NB (pad 256)
    int*   esrc      = boff + 256;              // E
    float* buf       = (float*)(esrc + E);      // N*HID (scratch GEMM output)
    float* outf      = (float*)d_out;           // N*HID (also used as intermediate)

    hipMemsetAsync(cnt, 0, sizeof(int) * 2 * (size_t)N, stream);  // cnt + cursor

    count_kernel<<<(E + 255) / 256, 256, 0, stream>>>(dst, cnt, E);
    scan_blocksum<<<NB, 256, 0, stream>>>(cnt, bsum, N);
    scan_partials<<<1, 256, 0, stream>>>(bsum, boff, row_start, NB, N);
    scan_final<<<NB, 256, 0, stream>>>(cnt, boff, row_start, dinv, N);
    scatter_kernel<<<(E + 255) / 256, 256, 0, stream>>>(src, dst, row_start, cursor, esrc, E);

    // layer 1: gemm -> buf, agg -> d_out
    gemm_kernel<<<(N + 127) / 128, 256, 0, stream>>>(x, W1, buf, N, K1);
    agg_kernel<<<N, 128, 0, stream>>>(buf, row_start, esrc, dinv, b1, outf, N);
    // layer 2: gemm(d_out) -> buf, agg -> d_out
    gemm_kernel<<<(N + 127) / 128, 256, 0, stream>>>(outf, W2, buf, N, HID);
    agg_kernel<<<N, 128, 0, stream>>>(buf, row_start, esrc, dinv, b2, outf, N);
}

// Round 8
// 343.908 us; speedup vs baseline: 1.5204x; 1.1216x over previous
//
#include <hip/hip_runtime.h>
#include <hip/hip_fp16.h>

// GCN 2-layer forward on MI355X.
// Pipeline per call (all on `stream`, graph-capture safe):
//   memset(cnt,cursor) -> count(dst) -> 3-kernel decoupled scan (+dinv)
//   -> scatter(CSR by dst)
//   -> gemm(x,W1)->Hs16 (fp16, dinv-prescaled) -> agg+bias+relu -> d_out
//   -> gemm(d_out,W2)->Hs16 -> agg+bias+relu -> d_out
// NOTE: harness stages integer inputs as int32 -> edge_index is const int*.
// R4: parallel 3-kernel scan (110us -> ~5us).
// R5: GEMM 128x128 tile, 8x8 micro-tile (was 22 TF / VALUBusy 30%).
// R6: agg was HBM-bound (264MB @ 3.7TB/s, 71us). GEMM epilogue now emits
//     fp16 rows pre-scaled by dinv[s] -> gather traffic halved, dinv gather
//     and s_w LDS reads eliminated. Risk: absmax ~1-2e-3 (was 9.8e-4).
// R7: resubmit (R6 never ran - GPU acquisition timeout).

#define NNODES 50000

// ---- CSR build -------------------------------------------------------------

__global__ void count_kernel(const int* __restrict__ dst, int* __restrict__ cnt, int E) {
    int e = blockIdx.x * blockDim.x + threadIdx.x;
    if (e < E) atomicAdd(&cnt[dst[e]], 1);
}

// A: per-block (256-elem chunk) sum of cnt -> bsum[b]
__global__ __launch_bounds__(256) void scan_blocksum(const int* __restrict__ cnt,
                                                     int* __restrict__ bsum, int N) {
    __shared__ int ws[4];
    int i = blockIdx.x * 256 + threadIdx.x;
    int v = (i < N) ? cnt[i] : 0;
#pragma unroll
    for (int off = 1; off < 64; off <<= 1) v += __shfl_xor(v, off);
    int lane = threadIdx.x & 63, w = threadIdx.x >> 6;
    if (lane == 0) ws[w] = v;
    __syncthreads();
    if (threadIdx.x == 0) bsum[blockIdx.x] = ws[0] + ws[1] + ws[2] + ws[3];
}

// B: single block scans NB (<=256) partials -> exclusive boff; writes row_start[N]
__global__ __launch_bounds__(256) void scan_partials(const int* __restrict__ bsum,
                                                     int* __restrict__ boff,
                                                     int* __restrict__ row_start,
                                                     int NB, int N) {
    __shared__ int ws[4];
    int t = threadIdx.x;
    int v = (t < NB) ? bsum[t] : 0;
    int lane = t & 63, w = t >> 6;
    int inc = v;
#pragma unroll
    for (int off = 1; off < 64; off <<= 1) {
        int n = __shfl_up(inc, off);
        if (lane >= off) inc += n;
    }
    if (lane == 63) ws[w] = inc;
    __syncthreads();
    int woff = 0;
    for (int k = 0; k < w; ++k) woff += ws[k];
    int excl = woff + inc - v;
    if (t < NB) boff[t] = excl;
    if (t == NB - 1) row_start[N] = excl + v;  // grand total = E
}

// C: per-block exclusive scan of its chunk + boff[b] -> row_start; also dinv
__global__ __launch_bounds__(256) void scan_final(const int* __restrict__ cnt,
                                                  const int* __restrict__ boff,
                                                  int* __restrict__ row_start,
                                                  float* __restrict__ dinv, int N) {
    __shared__ int ws[4];
    int i = blockIdx.x * 256 + threadIdx.x;
    int v = (i < N) ? cnt[i] : 0;
    int lane = threadIdx.x & 63, w = threadIdx.x >> 6;
    int inc = v;
#pragma unroll
    for (int off = 1; off < 64; off <<= 1) {
        int n = __shfl_up(inc, off);
        if (lane >= off) inc += n;
    }
    if (lane == 63) ws[w] = inc;
    __syncthreads();
    int woff = 0;
    for (int k = 0; k < w; ++k) woff += ws[k];
    if (i < N) {
        row_start[i] = boff[blockIdx.x] + woff + inc - v;
        dinv[i] = rsqrtf((float)(v + 1));  // +1 self-loop; deg>=1 always
    }
}

__global__ void scatter_kernel(const int* __restrict__ src, const int* __restrict__ dst,
                               const int* __restrict__ row_start, int* __restrict__ cursor,
                               int* __restrict__ esrc, int E) {
    int e = blockIdx.x * blockDim.x + threadIdx.x;
    if (e < E) {
        int d = dst[e];
        int p = row_start[d] + atomicAdd(&cursor[d], 1);
        esrc[p] = src[e];
    }
}

// ---- GEMM: Hs16[M x 128] = fp16( dinv[m] * (A[M x K] @ W[K x 128]) ) -------
// 128x128 block tile, 256 threads, 8x8 micro-tile. A tile row-major stride 34
// (broadcast scalar reads, <=2-way alias); B cols split {tx*4, 64+tx*4} so each
// ds_read_b128 spans 256B (2-way alias = free). VALU-bound by design.

__global__ __launch_bounds__(256) void gemm_kernel(const float* __restrict__ A,
                                                   const float* __restrict__ W,
                                                   const float* __restrict__ dinv,
                                                   __half* __restrict__ Hs,
                                                   int M, int K) {
    constexpr int BM = 128, BN = 128, BK = 32, LDA = BK + 2;  // 34
    __shared__ float sA[BM * LDA];
    __shared__ float sW[BK][BN];
    int t = threadIdx.x;
    int row0 = blockIdx.x * BM;
    int tx = t & 15;   // cols tx*4..+3 and 64+tx*4..+3
    int ty = t >> 4;   // rows ty*8..+7
    float acc[8][8] = {};

    for (int k0 = 0; k0 < K; k0 += BK) {
        // stage A: BM x BK as float2 (rows 8B-aligned: K is even)
#pragma unroll
        for (int j = 0; j < 8; ++j) {
            int s  = t + 256 * j;      // 0..2047
            int r  = s >> 4;           // 0..127
            int c2 = s & 15;           // float2 slot in row
            int gr = row0 + r;
            int gk = k0 + c2 * 2;
            float2 v = make_float2(0.f, 0.f);
            if (gr < M) {
                if (gk + 1 < K)      v = *reinterpret_cast<const float2*>(&A[(size_t)gr * K + gk]);
                else if (gk < K)     v.x = A[(size_t)gr * K + gk];
            }
            *reinterpret_cast<float2*>(&sA[r * LDA + c2 * 2]) = v;
        }
        // stage W: BK x BN as float4
#pragma unroll
        for (int j = 0; j < 4; ++j) {
            int s  = t + 256 * j;      // 0..1023
            int r  = s >> 5;           // 0..31
            int c4 = s & 31;
            int gk = k0 + r;
            float4 v = make_float4(0.f, 0.f, 0.f, 0.f);
            if (gk < K) v = *reinterpret_cast<const float4*>(&W[(size_t)gk * BN + c4 * 4]);
            *reinterpret_cast<float4*>(&sW[r][c4 * 4]) = v;
        }
        __syncthreads();
#pragma unroll 4
        for (int kk = 0; kk < BK; ++kk) {
            float4 b0 = *reinterpret_cast<const float4*>(&sW[kk][tx * 4]);
            float4 b1 = *reinterpret_cast<const float4*>(&sW[kk][64 + tx * 4]);
            float a[8];
#pragma unroll
            for (int i = 0; i < 8; ++i) a[i] = sA[(ty * 8 + i) * LDA + kk];
#pragma unroll
            for (int i = 0; i < 8; ++i) {
                acc[i][0] = fmaf(a[i], b0.x, acc[i][0]);
                acc[i][1] = fmaf(a[i], b0.y, acc[i][1]);
                acc[i][2] = fmaf(a[i], b0.z, acc[i][2]);
                acc[i][3] = fmaf(a[i], b0.w, acc[i][3]);
                acc[i][4] = fmaf(a[i], b1.x, acc[i][4]);
                acc[i][5] = fmaf(a[i], b1.y, acc[i][5]);
                acc[i][6] = fmaf(a[i], b1.z, acc[i][6]);
                acc[i][7] = fmaf(a[i], b1.w, acc[i][7]);
            }
        }
        __syncthreads();
    }
#pragma unroll
    for (int i = 0; i < 8; ++i) {
        int gr = row0 + ty * 8 + i;
        if (gr < M) {
            float di = dinv[gr];
            __half2 p0 = __floats2half2_rn(di * acc[i][0], di * acc[i][1]);
            __half2 p1 = __floats2half2_rn(di * acc[i][2], di * acc[i][3]);
            __half2 p2 = __floats2half2_rn(di * acc[i][4], di * acc[i][5]);
            __half2 p3 = __floats2half2_rn(di * acc[i][6], di * acc[i][7]);
            uint2 pk0, pk1;
            pk0.x = *reinterpret_cast<unsigned int*>(&p0);
            pk0.y = *reinterpret_cast<unsigned int*>(&p1);
            pk1.x = *reinterpret_cast<unsigned int*>(&p2);
            pk1.y = *reinterpret_cast<unsigned int*>(&p3);
            *reinterpret_cast<uint2*>(&Hs[(size_t)gr * BN + tx * 4])      = pk0;
            *reinterpret_cast<uint2*>(&Hs[(size_t)gr * BN + 64 + tx * 4]) = pk1;
        }
    }
}

// ---- Aggregation: out[i,f] = relu( dinv[i]*(sum_e Hs[s,f] + Hs[i,f]) + b[f] )
// where Hs[s] = fp16(dinv[s]*h[s]). One 128-thread block per node; thread f
// owns feature f. Edge index list staged in LDS; no per-edge weight needed.

__global__ __launch_bounds__(128) void agg_kernel(const __half* __restrict__ Hs,
                                                  const int* __restrict__ row_start,
                                                  const int* __restrict__ esrc,
                                                  const float* __restrict__ dinv,
                                                  const float* __restrict__ bias,
                                                  float* __restrict__ out, int N) {
    constexpr int F = 128;
    __shared__ int s_idx[128];
    int i = blockIdx.x;
    int f = threadIdx.x;
    int beg = row_start[i];
    int end = row_start[i + 1];
    float acc0 = 0.f, acc1 = 0.f;
    for (int base = beg; base < end; base += 128) {
        int m = end - base; if (m > 128) m = 128;
        __syncthreads();
        if (f < m) s_idx[f] = esrc[base + f];
        __syncthreads();
        int j = 0;
        for (; j + 4 <= m; j += 4) {
            float v0 = __half2float(Hs[(size_t)s_idx[j + 0] * F + f]);
            float v1 = __half2float(Hs[(size_t)s_idx[j + 1] * F + f]);
            float v2 = __half2float(Hs[(size_t)s_idx[j + 2] * F + f]);
            float v3 = __half2float(Hs[(size_t)s_idx[j + 3] * F + f]);
            acc0 += v0 + v2;
            acc1 += v1 + v3;
        }
        for (; j < m; ++j)
            acc0 += __half2float(Hs[(size_t)s_idx[j] * F + f]);
    }
    float self = __half2float(Hs[(size_t)i * F + f]);
    float v = fmaf(dinv[i], acc0 + acc1 + self, bias[f]);
    out[(size_t)i * F + f] = fmaxf(v, 0.f);
}

// ---- launch ----------------------------------------------------------------

extern "C" void kernel_launch(void* const* d_in, const int* in_sizes, int n_in,
                              void* d_out, int out_size, void* d_ws, size_t ws_size,
                              hipStream_t stream) {
    const float* x  = (const float*)d_in[0];
    const int*   ei = (const int*)d_in[1];     // int32 per harness staging
    const float* W1 = (const float*)d_in[2];
    const float* b1 = (const float*)d_in[3];
    const float* W2 = (const float*)d_in[4];
    const float* b2 = (const float*)d_in[5];

    const int N   = NNODES;
    const int E   = in_sizes[1] / 2;       // 800000
    const int K1  = in_sizes[0] / N;       // 130
    const int HID = in_sizes[3];           // 128
    const int NB  = (N + 255) / 256;       // scan blocks (196)

    const int* src = ei;
    const int* dst = ei + E;

    // workspace layout (all 16B-aligned by construction)
    int*    cnt       = (int*)d_ws;              // N
    int*    cursor    = cnt + N;                 // N
    int*    row_start = cursor + N;              // N+1 (padded to N+4)
    float*  dinv      = (float*)(row_start + N + 4);
    int*    bsum      = (int*)(dinv + N);        // NB (pad 256)
    int*    boff      = bsum + 256;              // NB (pad 256)
    int*    esrc      = boff + 256;              // E
    __half* Hs        = (__half*)(esrc + E);     // N*HID halves (12.8 MB)
    float*  outf      = (float*)d_out;           // N*HID fp32 (also intermediate)

    hipMemsetAsync(cnt, 0, sizeof(int) * 2 * (size_t)N, stream);  // cnt + cursor

    count_kernel<<<(E + 255) / 256, 256, 0, stream>>>(dst, cnt, E);
    scan_blocksum<<<NB, 256, 0, stream>>>(cnt, bsum, N);
    scan_partials<<<1, 256, 0, stream>>>(bsum, boff, row_start, NB, N);
    scan_final<<<NB, 256, 0, stream>>>(cnt, boff, row_start, dinv, N);
    scatter_kernel<<<(E + 255) / 256, 256, 0, stream>>>(src, dst, row_start, cursor, esrc, E);

    // layer 1: gemm -> Hs (fp16 prescaled), agg -> d_out
    gemm_kernel<<<(N + 127) / 128, 256, 0, stream>>>(x, W1, dinv, Hs, N, K1);
    agg_kernel<<<N, 128, 0, stream>>>(Hs, row_start, esrc, dinv, b1, outf, N);
    // layer 2: gemm(d_out) -> Hs, agg -> d_out
    gemm_kernel<<<(N + 127) / 128, 256, 0, stream>>>(outf, W2, dinv, Hs, N, HID);
    agg_kernel<<<N, 128, 0, stream>>>(Hs, row_start, esrc, dinv, b2, outf, N);
}

// Round 9
// 327.233 us; speedup vs baseline: 1.5978x; 1.0510x over previous
//
#include <hip/hip_runtime.h>
#include <hip/hip_fp16.h>

// GCN 2-layer forward on MI355X.
// Pipeline per call (all on `stream`, graph-capture safe):
//   memset(cnt,cursor) -> count(dst) -> 3-kernel decoupled scan (+dinv)
//   -> scatter(CSR by dst, XCD-partitioned)
//   -> gemm(x,W1)->Hs16 (fp16, dinv-prescaled) -> agg+bias+relu -> d_out
//   -> gemm(d_out,W2)->Hs16 -> agg+bias+relu -> d_out
// NOTE: harness stages integer inputs as int32 -> edge_index is const int*.
// R4: parallel 3-kernel scan (110us -> ~5us).
// R5: GEMM 128x128 tile, 8x8 micro-tile (22 TF -> 31 TF).
// R6/7: fp16 dinv-prescaled gather table; agg 71us -> <52us. absmax 3.9e-3.
// R8: (a) GEMM BM 128->64: grid 391->782 blocks (occupancy was 14%, 1 wave/SIMD
//     couldn't hide staging latency). (b) scatter was 53us with WRITE_SIZE
//     55.5MB for 3.2MB payload (random 4B stores = 64B line writebacks across
//     8 non-coherent XCD L2s). Now XCD-partitioned: owner=blockIdx&7 keeps only
//     its 1/8 dst-range -> writes cluster in one 400KB window per XCD L2.

#define NNODES 50000

// ---- CSR build -------------------------------------------------------------

__global__ void count_kernel(const int* __restrict__ dst, int* __restrict__ cnt, int E) {
    int e = blockIdx.x * blockDim.x + threadIdx.x;
    if (e < E) atomicAdd(&cnt[dst[e]], 1);
}

// A: per-block (256-elem chunk) sum of cnt -> bsum[b]
__global__ __launch_bounds__(256) void scan_blocksum(const int* __restrict__ cnt,
                                                     int* __restrict__ bsum, int N) {
    __shared__ int ws[4];
    int i = blockIdx.x * 256 + threadIdx.x;
    int v = (i < N) ? cnt[i] : 0;
#pragma unroll
    for (int off = 1; off < 64; off <<= 1) v += __shfl_xor(v, off);
    int lane = threadIdx.x & 63, w = threadIdx.x >> 6;
    if (lane == 0) ws[w] = v;
    __syncthreads();
    if (threadIdx.x == 0) bsum[blockIdx.x] = ws[0] + ws[1] + ws[2] + ws[3];
}

// B: single block scans NB (<=256) partials -> exclusive boff; writes row_start[N]
__global__ __launch_bounds__(256) void scan_partials(const int* __restrict__ bsum,
                                                     int* __restrict__ boff,
                                                     int* __restrict__ row_start,
                                                     int NB, int N) {
    __shared__ int ws[4];
    int t = threadIdx.x;
    int v = (t < NB) ? bsum[t] : 0;
    int lane = t & 63, w = t >> 6;
    int inc = v;
#pragma unroll
    for (int off = 1; off < 64; off <<= 1) {
        int n = __shfl_up(inc, off);
        if (lane >= off) inc += n;
    }
    if (lane == 63) ws[w] = inc;
    __syncthreads();
    int woff = 0;
    for (int k = 0; k < w; ++k) woff += ws[k];
    int excl = woff + inc - v;
    if (t < NB) boff[t] = excl;
    if (t == NB - 1) row_start[N] = excl + v;  // grand total = E
}

// C: per-block exclusive scan of its chunk + boff[b] -> row_start; also dinv
__global__ __launch_bounds__(256) void scan_final(const int* __restrict__ cnt,
                                                  const int* __restrict__ boff,
                                                  int* __restrict__ row_start,
                                                  float* __restrict__ dinv, int N) {
    __shared__ int ws[4];
    int i = blockIdx.x * 256 + threadIdx.x;
    int v = (i < N) ? cnt[i] : 0;
    int lane = threadIdx.x & 63, w = threadIdx.x >> 6;
    int inc = v;
#pragma unroll
    for (int off = 1; off < 64; off <<= 1) {
        int n = __shfl_up(inc, off);
        if (lane >= off) inc += n;
    }
    if (lane == 63) ws[w] = inc;
    __syncthreads();
    int woff = 0;
    for (int k = 0; k < w; ++k) woff += ws[k];
    if (i < N) {
        row_start[i] = boff[blockIdx.x] + woff + inc - v;
        dinv[i] = rsqrtf((float)(v + 1));  // +1 self-loop; deg>=1 always
    }
}

// XCD-partitioned scatter: owner = blockIdx&7; each owner group (256 blocks)
// strides all E edges, keeping only dst in its node range. All esrc writes from
// one owner land in a ~400KB contiguous CSR window -> L2-local accumulation.
__global__ __launch_bounds__(256) void scatter_kernel(const int* __restrict__ src,
                                                      const int* __restrict__ dst,
                                                      const int* __restrict__ row_start,
                                                      int* __restrict__ cursor,
                                                      int* __restrict__ esrc,
                                                      int E, int npo) {
    int owner = blockIdx.x & 7;
    int nblk  = gridDim.x >> 3;
    int bo    = blockIdx.x >> 3;
    int lo = owner * npo;
    int hi = lo + npo;
    for (int e = bo * 256 + threadIdx.x; e < E; e += nblk * 256) {
        int d = dst[e];
        if (d >= lo && d < hi) {
            int p = row_start[d] + atomicAdd(&cursor[d], 1);
            esrc[p] = src[e];
        }
    }
}

// ---- GEMM: Hs16[M x 128] = fp16( dinv[m] * (A[M x K] @ W[K x 128]) ) -------
// 64x128 block tile, 256 threads, 4x8 micro-tile (cols split {tx*4, 64+tx*4}).
// Grid ~782 blocks -> ~3 blocks/CU so staging of one block overlaps compute of
// others. A tile stride 34 (broadcast scalar reads, <=2-way alias).

__global__ __launch_bounds__(256) void gemm_kernel(const float* __restrict__ A,
                                                   const float* __restrict__ W,
                                                   const float* __restrict__ dinv,
                                                   __half* __restrict__ Hs,
                                                   int M, int K) {
    constexpr int BM = 64, BN = 128, BK = 32, LDA = BK + 2;  // 34
    __shared__ float sA[BM * LDA];
    __shared__ float sW[BK][BN];
    int t = threadIdx.x;
    int row0 = blockIdx.x * BM;
    int tx = t & 15;   // cols tx*4..+3 and 64+tx*4..+3
    int ty = t >> 4;   // rows ty*4..+3
    float acc[4][8] = {};

    for (int k0 = 0; k0 < K; k0 += BK) {
        // stage A: BM x BK as float2 (rows 8B-aligned: K is even)
#pragma unroll
        for (int j = 0; j < 4; ++j) {
            int s  = t + 256 * j;      // 0..1023
            int r  = s >> 4;           // 0..63
            int c2 = s & 15;           // float2 slot in row
            int gr = row0 + r;
            int gk = k0 + c2 * 2;
            float2 v = make_float2(0.f, 0.f);
            if (gr < M) {
                if (gk + 1 < K)      v = *reinterpret_cast<const float2*>(&A[(size_t)gr * K + gk]);
                else if (gk < K)     v.x = A[(size_t)gr * K + gk];
            }
            *reinterpret_cast<float2*>(&sA[r * LDA + c2 * 2]) = v;
        }
        // stage W: BK x BN as float4
#pragma unroll
        for (int j = 0; j < 4; ++j) {
            int s  = t + 256 * j;      // 0..1023
            int r  = s >> 5;           // 0..31
            int c4 = s & 31;
            int gk = k0 + r;
            float4 v = make_float4(0.f, 0.f, 0.f, 0.f);
            if (gk < K) v = *reinterpret_cast<const float4*>(&W[(size_t)gk * BN + c4 * 4]);
            *reinterpret_cast<float4*>(&sW[r][c4 * 4]) = v;
        }
        __syncthreads();
#pragma unroll 4
        for (int kk = 0; kk < BK; ++kk) {
            float4 b0 = *reinterpret_cast<const float4*>(&sW[kk][tx * 4]);
            float4 b1 = *reinterpret_cast<const float4*>(&sW[kk][64 + tx * 4]);
            float a[4];
#pragma unroll
            for (int i = 0; i < 4; ++i) a[i] = sA[(ty * 4 + i) * LDA + kk];
#pragma unroll
            for (int i = 0; i < 4; ++i) {
                acc[i][0] = fmaf(a[i], b0.x, acc[i][0]);
                acc[i][1] = fmaf(a[i], b0.y, acc[i][1]);
                acc[i][2] = fmaf(a[i], b0.z, acc[i][2]);
                acc[i][3] = fmaf(a[i], b0.w, acc[i][3]);
                acc[i][4] = fmaf(a[i], b1.x, acc[i][4]);
                acc[i][5] = fmaf(a[i], b1.y, acc[i][5]);
                acc[i][6] = fmaf(a[i], b1.z, acc[i][6]);
                acc[i][7] = fmaf(a[i], b1.w, acc[i][7]);
            }
        }
        __syncthreads();
    }
#pragma unroll
    for (int i = 0; i < 4; ++i) {
        int gr = row0 + ty * 4 + i;
        if (gr < M) {
            float di = dinv[gr];
            __half2 p0 = __floats2half2_rn(di * acc[i][0], di * acc[i][1]);
            __half2 p1 = __floats2half2_rn(di * acc[i][2], di * acc[i][3]);
            __half2 p2 = __floats2half2_rn(di * acc[i][4], di * acc[i][5]);
            __half2 p3 = __floats2half2_rn(di * acc[i][6], di * acc[i][7]);
            uint2 pk0, pk1;
            pk0.x = *reinterpret_cast<unsigned int*>(&p0);
            pk0.y = *reinterpret_cast<unsigned int*>(&p1);
            pk1.x = *reinterpret_cast<unsigned int*>(&p2);
            pk1.y = *reinterpret_cast<unsigned int*>(&p3);
            *reinterpret_cast<uint2*>(&Hs[(size_t)gr * BN + tx * 4])      = pk0;
            *reinterpret_cast<uint2*>(&Hs[(size_t)gr * BN + 64 + tx * 4]) = pk1;
        }
    }
}

// ---- Aggregation: out[i,f] = relu( dinv[i]*(sum_e Hs[s,f] + Hs[i,f]) + b[f] )
// where Hs[s] = fp16(dinv[s]*h[s]). One 128-thread block per node; thread f
// owns feature f. Edge index list staged in LDS; no per-edge weight needed.

__global__ __launch_bounds__(128) void agg_kernel(const __half* __restrict__ Hs,
                                                  const int* __restrict__ row_start,
                                                  const int* __restrict__ esrc,
                                                  const float* __restrict__ dinv,
                                                  const float* __restrict__ bias,
                                                  float* __restrict__ out, int N) {
    constexpr int F = 128;
    __shared__ int s_idx[128];
    int i = blockIdx.x;
    int f = threadIdx.x;
    int beg = row_start[i];
    int end = row_start[i + 1];
    float acc0 = 0.f, acc1 = 0.f;
    for (int base = beg; base < end; base += 128) {
        int m = end - base; if (m > 128) m = 128;
        __syncthreads();
        if (f < m) s_idx[f] = esrc[base + f];
        __syncthreads();
        int j = 0;
        for (; j + 4 <= m; j += 4) {
            float v0 = __half2float(Hs[(size_t)s_idx[j + 0] * F + f]);
            float v1 = __half2float(Hs[(size_t)s_idx[j + 1] * F + f]);
            float v2 = __half2float(Hs[(size_t)s_idx[j + 2] * F + f]);
            float v3 = __half2float(Hs[(size_t)s_idx[j + 3] * F + f]);
            acc0 += v0 + v2;
            acc1 += v1 + v3;
        }
        for (; j < m; ++j)
            acc0 += __half2float(Hs[(size_t)s_idx[j] * F + f]);
    }
    float self = __half2float(Hs[(size_t)i * F + f]);
    float v = fmaf(dinv[i], acc0 + acc1 + self, bias[f]);
    out[(size_t)i * F + f] = fmaxf(v, 0.f);
}

// ---- launch ----------------------------------------------------------------

extern "C" void kernel_launch(void* const* d_in, const int* in_sizes, int n_in,
                              void* d_out, int out_size, void* d_ws, size_t ws_size,
                              hipStream_t stream) {
    const float* x  = (const float*)d_in[0];
    const int*   ei = (const int*)d_in[1];     // int32 per harness staging
    const float* W1 = (const float*)d_in[2];
    const float* b1 = (const float*)d_in[3];
    const float* W2 = (const float*)d_in[4];
    const float* b2 = (const float*)d_in[5];

    const int N   = NNODES;
    const int E   = in_sizes[1] / 2;       // 800000
    const int K1  = in_sizes[0] / N;       // 130
    const int HID = in_sizes[3];           // 128
    const int NB  = (N + 255) / 256;       // scan blocks (196)
    const int NPO = (N + 7) / 8;           // nodes per scatter owner (6250)

    const int* src = ei;
    const int* dst = ei + E;

    // workspace layout (all 16B-aligned by construction)
    int*    cnt       = (int*)d_ws;              // N
    int*    cursor    = cnt + N;                 // N
    int*    row_start = cursor + N;              // N+1 (padded to N+4)
    float*  dinv      = (float*)(row_start + N + 4);
    int*    bsum      = (int*)(dinv + N);        // NB (pad 256)
    int*    boff      = bsum + 256;              // NB (pad 256)
    int*    esrc      = boff + 256;              // E
    __half* Hs        = (__half*)(esrc + E);     // N*HID halves (12.8 MB)
    float*  outf      = (float*)d_out;           // N*HID fp32 (also intermediate)

    hipMemsetAsync(cnt, 0, sizeof(int) * 2 * (size_t)N, stream);  // cnt + cursor

    count_kernel<<<(E + 255) / 256, 256, 0, stream>>>(dst, cnt, E);
    scan_blocksum<<<NB, 256, 0, stream>>>(cnt, bsum, N);
    scan_partials<<<1, 256, 0, stream>>>(bsum, boff, row_start, NB, N);
    scan_final<<<NB, 256, 0, stream>>>(cnt, boff, row_start, dinv, N);
    scatter_kernel<<<2048, 256, 0, stream>>>(src, dst, row_start, cursor, esrc, E, NPO);

    // layer 1: gemm -> Hs (fp16 prescaled), agg -> d_out
    gemm_kernel<<<(N + 63) / 64, 256, 0, stream>>>(x, W1, dinv, Hs, N, K1);
    agg_kernel<<<N, 128, 0, stream>>>(Hs, row_start, esrc, dinv, b1, outf, N);
    // layer 2: gemm(d_out) -> Hs, agg -> d_out
    gemm_kernel<<<(N + 63) / 64, 256, 0, stream>>>(outf, W2, dinv, Hs, N, HID);
    agg_kernel<<<N, 128, 0, stream>>>(Hs, row_start, esrc, dinv, b2, outf, N);
}

// Round 10
// 316.670 us; speedup vs baseline: 1.6511x; 1.0334x over previous
//
#include <hip/hip_runtime.h>
#include <hip/hip_fp16.h>

// GCN 2-layer forward on MI355X.
// Pipeline per call (all on `stream`, graph-capture safe):
//   memset(cnt,cursor) -> count(dst) -> 3-kernel decoupled scan (+dinv)
//   -> scatter(CSR by dst, XCD-partitioned)
//   -> gemm(x,W1)->Hs16 (fp16, dinv-prescaled) -> agg+bias+relu -> d_out
//   -> gemm(d_out,W2)->Hs16 -> agg+bias+relu -> d_out
// NOTE: harness stages integer inputs as int32 -> edge_index is const int*.
// R4: parallel 3-kernel scan (110us -> ~5us).
// R5: GEMM 128x128 tile, 8x8 micro-tile (22 TF -> 31 TF).
// R6/7: fp16 dinv-prescaled gather table; agg 71us -> 49.5us. absmax 3.9e-3.
// R8: GEMM BM->64 (occupancy); scatter XCD-partitioned (53us -> <49).
// R9: agg FETCH=120MB == compulsory 8-XCD table duplication (floor). 49.5us
//     with VALUBusy 35% => gather-issue-bound (2 wave-VMEM ushort instrs/edge).
//     Rewrite: 1 wave/node, edge list in registers (shfl, no LDS/syncthreads),
//     uint2 gathers: 2 edges per VMEM instr (4x fewer instrs, 8B/lane).

#define NNODES 50000

// ---- CSR build -------------------------------------------------------------

__global__ void count_kernel(const int* __restrict__ dst, int* __restrict__ cnt, int E) {
    int e = blockIdx.x * blockDim.x + threadIdx.x;
    if (e < E) atomicAdd(&cnt[dst[e]], 1);
}

// A: per-block (256-elem chunk) sum of cnt -> bsum[b]
__global__ __launch_bounds__(256) void scan_blocksum(const int* __restrict__ cnt,
                                                     int* __restrict__ bsum, int N) {
    __shared__ int ws[4];
    int i = blockIdx.x * 256 + threadIdx.x;
    int v = (i < N) ? cnt[i] : 0;
#pragma unroll
    for (int off = 1; off < 64; off <<= 1) v += __shfl_xor(v, off);
    int lane = threadIdx.x & 63, w = threadIdx.x >> 6;
    if (lane == 0) ws[w] = v;
    __syncthreads();
    if (threadIdx.x == 0) bsum[blockIdx.x] = ws[0] + ws[1] + ws[2] + ws[3];
}

// B: single block scans NB (<=256) partials -> exclusive boff; writes row_start[N]
__global__ __launch_bounds__(256) void scan_partials(const int* __restrict__ bsum,
                                                     int* __restrict__ boff,
                                                     int* __restrict__ row_start,
                                                     int NB, int N) {
    __shared__ int ws[4];
    int t = threadIdx.x;
    int v = (t < NB) ? bsum[t] : 0;
    int lane = t & 63, w = t >> 6;
    int inc = v;
#pragma unroll
    for (int off = 1; off < 64; off <<= 1) {
        int n = __shfl_up(inc, off);
        if (lane >= off) inc += n;
    }
    if (lane == 63) ws[w] = inc;
    __syncthreads();
    int woff = 0;
    for (int k = 0; k < w; ++k) woff += ws[k];
    int excl = woff + inc - v;
    if (t < NB) boff[t] = excl;
    if (t == NB - 1) row_start[N] = excl + v;  // grand total = E
}

// C: per-block exclusive scan of its chunk + boff[b] -> row_start; also dinv
__global__ __launch_bounds__(256) void scan_final(const int* __restrict__ cnt,
                                                  const int* __restrict__ boff,
                                                  int* __restrict__ row_start,
                                                  float* __restrict__ dinv, int N) {
    __shared__ int ws[4];
    int i = blockIdx.x * 256 + threadIdx.x;
    int v = (i < N) ? cnt[i] : 0;
    int lane = threadIdx.x & 63, w = threadIdx.x >> 6;
    int inc = v;
#pragma unroll
    for (int off = 1; off < 64; off <<= 1) {
        int n = __shfl_up(inc, off);
        if (lane >= off) inc += n;
    }
    if (lane == 63) ws[w] = inc;
    __syncthreads();
    int woff = 0;
    for (int k = 0; k < w; ++k) woff += ws[k];
    if (i < N) {
        row_start[i] = boff[blockIdx.x] + woff + inc - v;
        dinv[i] = rsqrtf((float)(v + 1));  // +1 self-loop; deg>=1 always
    }
}

// XCD-partitioned scatter: owner = blockIdx&7; each owner group strides all E
// edges, keeping only dst in its node range -> writes cluster per XCD L2.
__global__ __launch_bounds__(256) void scatter_kernel(const int* __restrict__ src,
                                                      const int* __restrict__ dst,
                                                      const int* __restrict__ row_start,
                                                      int* __restrict__ cursor,
                                                      int* __restrict__ esrc,
                                                      int E, int npo) {
    int owner = blockIdx.x & 7;
    int nblk  = gridDim.x >> 3;
    int bo    = blockIdx.x >> 3;
    int lo = owner * npo;
    int hi = lo + npo;
    for (int e = bo * 256 + threadIdx.x; e < E; e += nblk * 256) {
        int d = dst[e];
        if (d >= lo && d < hi) {
            int p = row_start[d] + atomicAdd(&cursor[d], 1);
            esrc[p] = src[e];
        }
    }
}

// ---- GEMM: Hs16[M x 128] = fp16( dinv[m] * (A[M x K] @ W[K x 128]) ) -------
// 64x128 block tile, 256 threads, 4x8 micro-tile (cols split {tx*4, 64+tx*4}).

__global__ __launch_bounds__(256) void gemm_kernel(const float* __restrict__ A,
                                                   const float* __restrict__ W,
                                                   const float* __restrict__ dinv,
                                                   __half* __restrict__ Hs,
                                                   int M, int K) {
    constexpr int BM = 64, BN = 128, BK = 32, LDA = BK + 2;  // 34
    __shared__ float sA[BM * LDA];
    __shared__ float sW[BK][BN];
    int t = threadIdx.x;
    int row0 = blockIdx.x * BM;
    int tx = t & 15;   // cols tx*4..+3 and 64+tx*4..+3
    int ty = t >> 4;   // rows ty*4..+3
    float acc[4][8] = {};

    for (int k0 = 0; k0 < K; k0 += BK) {
#pragma unroll
        for (int j = 0; j < 4; ++j) {
            int s  = t + 256 * j;      // 0..1023
            int r  = s >> 4;           // 0..63
            int c2 = s & 15;
            int gr = row0 + r;
            int gk = k0 + c2 * 2;
            float2 v = make_float2(0.f, 0.f);
            if (gr < M) {
                if (gk + 1 < K)      v = *reinterpret_cast<const float2*>(&A[(size_t)gr * K + gk]);
                else if (gk < K)     v.x = A[(size_t)gr * K + gk];
            }
            *reinterpret_cast<float2*>(&sA[r * LDA + c2 * 2]) = v;
        }
#pragma unroll
        for (int j = 0; j < 4; ++j) {
            int s  = t + 256 * j;      // 0..1023
            int r  = s >> 5;           // 0..31
            int c4 = s & 31;
            int gk = k0 + r;
            float4 v = make_float4(0.f, 0.f, 0.f, 0.f);
            if (gk < K) v = *reinterpret_cast<const float4*>(&W[(size_t)gk * BN + c4 * 4]);
            *reinterpret_cast<float4*>(&sW[r][c4 * 4]) = v;
        }
        __syncthreads();
#pragma unroll 4
        for (int kk = 0; kk < BK; ++kk) {
            float4 b0 = *reinterpret_cast<const float4*>(&sW[kk][tx * 4]);
            float4 b1 = *reinterpret_cast<const float4*>(&sW[kk][64 + tx * 4]);
            float a[4];
#pragma unroll
            for (int i = 0; i < 4; ++i) a[i] = sA[(ty * 4 + i) * LDA + kk];
#pragma unroll
            for (int i = 0; i < 4; ++i) {
                acc[i][0] = fmaf(a[i], b0.x, acc[i][0]);
                acc[i][1] = fmaf(a[i], b0.y, acc[i][1]);
                acc[i][2] = fmaf(a[i], b0.z, acc[i][2]);
                acc[i][3] = fmaf(a[i], b0.w, acc[i][3]);
                acc[i][4] = fmaf(a[i], b1.x, acc[i][4]);
                acc[i][5] = fmaf(a[i], b1.y, acc[i][5]);
                acc[i][6] = fmaf(a[i], b1.z, acc[i][6]);
                acc[i][7] = fmaf(a[i], b1.w, acc[i][7]);
            }
        }
        __syncthreads();
    }
#pragma unroll
    for (int i = 0; i < 4; ++i) {
        int gr = row0 + ty * 4 + i;
        if (gr < M) {
            float di = dinv[gr];
            __half2 p0 = __floats2half2_rn(di * acc[i][0], di * acc[i][1]);
            __half2 p1 = __floats2half2_rn(di * acc[i][2], di * acc[i][3]);
            __half2 p2 = __floats2half2_rn(di * acc[i][4], di * acc[i][5]);
            __half2 p3 = __floats2half2_rn(di * acc[i][6], di * acc[i][7]);
            uint2 pk0, pk1;
            pk0.x = *reinterpret_cast<unsigned int*>(&p0);
            pk0.y = *reinterpret_cast<unsigned int*>(&p1);
            pk1.x = *reinterpret_cast<unsigned int*>(&p2);
            pk1.y = *reinterpret_cast<unsigned int*>(&p3);
            *reinterpret_cast<uint2*>(&Hs[(size_t)gr * BN + tx * 4])      = pk0;
            *reinterpret_cast<uint2*>(&Hs[(size_t)gr * BN + 64 + tx * 4]) = pk1;
        }
    }
}

// ---- Aggregation: out[i,f] = relu( dinv[i]*(sum_e Hs[s,f] + Hs[i,f]) + b[f] )
// One WAVE per node. Lane: c=lane&31 owns feature quad 4c..4c+3; h=lane>>5
// picks edge j+h -> one uint2 (4 fp16) per lane, 2 edges per VMEM instr.
// Edge list lives in a register (esrc[beg+lane]) and is broadcast via shfl;
// deg>64 falls back to direct loads. No LDS, no __syncthreads.

__global__ __launch_bounds__(256) void agg_kernel(const __half* __restrict__ Hs,
                                                  const int* __restrict__ row_start,
                                                  const int* __restrict__ esrc,
                                                  const float* __restrict__ dinv,
                                                  const float* __restrict__ bias,
                                                  float* __restrict__ out, int N) {
    constexpr int F = 128;
    int node = blockIdx.x * 4 + (threadIdx.x >> 6);
    if (node >= N) return;
    int lane = threadIdx.x & 63;
    int c = lane & 31;
    int h = lane >> 5;
    int beg = row_start[node];
    int deg = row_start[node + 1] - beg;

    int spre = (lane < deg) ? esrc[beg + lane] : 0;  // first 64 edges in regs

    float a0 = 0.f, a1 = 0.f, a2 = 0.f, a3 = 0.f;
    for (int j = 0; j < deg; j += 2) {
        int jj = j + h;
        int s;
        if (jj < 64) s = __shfl(spre, jj);
        else         s = (jj < deg) ? esrc[beg + jj] : 0;
        if (jj < deg) {
            uint2 v = *reinterpret_cast<const uint2*>(&Hs[(size_t)s * F + c * 4]);
            __half2 h0 = *reinterpret_cast<__half2*>(&v.x);
            __half2 h1 = *reinterpret_cast<__half2*>(&v.y);
            float2 f0 = __half22float2(h0);
            float2 f1 = __half22float2(h1);
            a0 += f0.x; a1 += f0.y; a2 += f1.x; a3 += f1.y;
        }
    }
    // combine the two edge-halves
    a0 += __shfl_xor(a0, 32);
    a1 += __shfl_xor(a1, 32);
    a2 += __shfl_xor(a2, 32);
    a3 += __shfl_xor(a3, 32);

    if (h == 0) {
        uint2 sv = *reinterpret_cast<const uint2*>(&Hs[(size_t)node * F + c * 4]);
        __half2 s0 = *reinterpret_cast<__half2*>(&sv.x);
        __half2 s1 = *reinterpret_cast<__half2*>(&sv.y);
        float2 g0 = __half22float2(s0);
        float2 g1 = __half22float2(s1);
        float4 b = *reinterpret_cast<const float4*>(&bias[c * 4]);
        float di = dinv[node];
        float4 r;
        r.x = fmaxf(fmaf(di, a0 + g0.x, b.x), 0.f);
        r.y = fmaxf(fmaf(di, a1 + g0.y, b.y), 0.f);
        r.z = fmaxf(fmaf(di, a2 + g1.x, b.z), 0.f);
        r.w = fmaxf(fmaf(di, a3 + g1.y, b.w), 0.f);
        *reinterpret_cast<float4*>(&out[(size_t)node * F + c * 4]) = r;
    }
}

// ---- launch ----------------------------------------------------------------

extern "C" void kernel_launch(void* const* d_in, const int* in_sizes, int n_in,
                              void* d_out, int out_size, void* d_ws, size_t ws_size,
                              hipStream_t stream) {
    const float* x  = (const float*)d_in[0];
    const int*   ei = (const int*)d_in[1];     // int32 per harness staging
    const float* W1 = (const float*)d_in[2];
    const float* b1 = (const float*)d_in[3];
    const float* W2 = (const float*)d_in[4];
    const float* b2 = (const float*)d_in[5];

    const int N   = NNODES;
    const int E   = in_sizes[1] / 2;       // 800000
    const int K1  = in_sizes[0] / N;       // 130
    const int HID = in_sizes[3];           // 128
    const int NB  = (N + 255) / 256;       // scan blocks (196)
    const int NPO = (N + 7) / 8;           // nodes per scatter owner (6250)

    const int* src = ei;
    const int* dst = ei + E;

    // workspace layout (all 16B-aligned by construction)
    int*    cnt       = (int*)d_ws;              // N
    int*    cursor    = cnt + N;                 // N
    int*    row_start = cursor + N;              // N+1 (padded to N+4)
    float*  dinv      = (float*)(row_start + N + 4);
    int*    bsum      = (int*)(dinv + N);        // NB (pad 256)
    int*    boff      = bsum + 256;              // NB (pad 256)
    int*    esrc      = boff + 256;              // E
    __half* Hs        = (__half*)(esrc + E);     // N*HID halves (12.8 MB)
    float*  outf      = (float*)d_out;           // N*HID fp32 (also intermediate)

    hipMemsetAsync(cnt, 0, sizeof(int) * 2 * (size_t)N, stream);  // cnt + cursor

    count_kernel<<<(E + 255) / 256, 256, 0, stream>>>(dst, cnt, E);
    scan_blocksum<<<NB, 256, 0, stream>>>(cnt, bsum, N);
    scan_partials<<<1, 256, 0, stream>>>(bsum, boff, row_start, NB, N);
    scan_final<<<NB, 256, 0, stream>>>(cnt, boff, row_start, dinv, N);
    scatter_kernel<<<2048, 256, 0, stream>>>(src, dst, row_start, cursor, esrc, E, NPO);

    // layer 1: gemm -> Hs (fp16 prescaled), agg -> d_out
    gemm_kernel<<<(N + 63) / 64, 256, 0, stream>>>(x, W1, dinv, Hs, N, K1);
    agg_kernel<<<(N + 3) / 4, 256, 0, stream>>>(Hs, row_start, esrc, dinv, b1, outf, N);
    // layer 2: gemm(d_out) -> Hs, agg -> d_out
    gemm_kernel<<<(N + 63) / 64, 256, 0, stream>>>(outf, W2, dinv, Hs, N, HID);
    agg_kernel<<<(N + 3) / 4, 256, 0, stream>>>(Hs, row_start, esrc, dinv, b2, outf, N);
}

// Round 12
// 307.930 us; speedup vs baseline: 1.6980x; 1.0284x over previous
//
#include <hip/hip_runtime.h>
#include <hip/hip_fp16.h>

// GCN 2-layer forward on MI355X.
// Pipeline per call (all on `stream`, graph-capture safe):
//   memset(cnt,cursor) -> count(dst) -> 3-kernel decoupled scan (+dinv)
//   -> scatter(CSR by dst, XCD-partitioned)
//   -> gemm(x,W1)->Hs16 (fp16, dinv-prescaled) -> agg+bias+relu -> d_out
//   -> gemm(d_out,W2)->Hs16 -> agg+bias+relu -> d_out
// NOTE: harness stages integer inputs as int32 -> edge_index is const int*.
// R4: parallel 3-kernel scan (110us -> ~5us).
// R5: GEMM 128x128 tile, 8x8 micro-tile (22 TF -> 31 TF).
// R6/7: fp16 dinv-prescaled gather table; agg 71us -> 49.5us. absmax 3.9e-3.
// R8: GEMM BM->64 (occupancy); scatter XCD-partitioned (53us -> <49).
// R9: agg 1 wave/node, reg edge list, uint2 gathers (49.5 -> 45us).
// R10: agg 8-wide gather batches; gemm A-tile transposed + reg prefetch.
// R11: FIX R10 UB: __shfl was moved inside `if (jj<deg)` -> ds_bpermute read
//      from exec-masked source lanes (undefined; e.g. deg=33,j0=32: reader
//      lane h=0 active, source lane 32 inactive). Shfl now executes under the
//      wave-uniform `jj<64` branch (jj parity never straddles 64), R9-style;
//      loads stay batched 8-wide for latency overlap.

#define NNODES 50000

// ---- CSR build -------------------------------------------------------------

__global__ void count_kernel(const int* __restrict__ dst, int* __restrict__ cnt, int E) {
    int e = blockIdx.x * blockDim.x + threadIdx.x;
    if (e < E) atomicAdd(&cnt[dst[e]], 1);
}

// A: per-block (256-elem chunk) sum of cnt -> bsum[b]
__global__ __launch_bounds__(256) void scan_blocksum(const int* __restrict__ cnt,
                                                     int* __restrict__ bsum, int N) {
    __shared__ int ws[4];
    int i = blockIdx.x * 256 + threadIdx.x;
    int v = (i < N) ? cnt[i] : 0;
#pragma unroll
    for (int off = 1; off < 64; off <<= 1) v += __shfl_xor(v, off);
    int lane = threadIdx.x & 63, w = threadIdx.x >> 6;
    if (lane == 0) ws[w] = v;
    __syncthreads();
    if (threadIdx.x == 0) bsum[blockIdx.x] = ws[0] + ws[1] + ws[2] + ws[3];
}

// B: single block scans NB (<=256) partials -> exclusive boff; writes row_start[N]
__global__ __launch_bounds__(256) void scan_partials(const int* __restrict__ bsum,
                                                     int* __restrict__ boff,
                                                     int* __restrict__ row_start,
                                                     int NB, int N) {
    __shared__ int ws[4];
    int t = threadIdx.x;
    int v = (t < NB) ? bsum[t] : 0;
    int lane = t & 63, w = t >> 6;
    int inc = v;
#pragma unroll
    for (int off = 1; off < 64; off <<= 1) {
        int n = __shfl_up(inc, off);
        if (lane >= off) inc += n;
    }
    if (lane == 63) ws[w] = inc;
    __syncthreads();
    int woff = 0;
    for (int k = 0; k < w; ++k) woff += ws[k];
    int excl = woff + inc - v;
    if (t < NB) boff[t] = excl;
    if (t == NB - 1) row_start[N] = excl + v;  // grand total = E
}

// C: per-block exclusive scan of its chunk + boff[b] -> row_start; also dinv
__global__ __launch_bounds__(256) void scan_final(const int* __restrict__ cnt,
                                                  const int* __restrict__ boff,
                                                  int* __restrict__ row_start,
                                                  float* __restrict__ dinv, int N) {
    __shared__ int ws[4];
    int i = blockIdx.x * 256 + threadIdx.x;
    int v = (i < N) ? cnt[i] : 0;
    int lane = threadIdx.x & 63, w = threadIdx.x >> 6;
    int inc = v;
#pragma unroll
    for (int off = 1; off < 64; off <<= 1) {
        int n = __shfl_up(inc, off);
        if (lane >= off) inc += n;
    }
    if (lane == 63) ws[w] = inc;
    __syncthreads();
    int woff = 0;
    for (int k = 0; k < w; ++k) woff += ws[k];
    if (i < N) {
        row_start[i] = boff[blockIdx.x] + woff + inc - v;
        dinv[i] = rsqrtf((float)(v + 1));  // +1 self-loop; deg>=1 always
    }
}

// XCD-partitioned scatter: owner = blockIdx&7; each owner group strides all E
// edges, keeping only dst in its node range -> writes cluster per XCD L2.
__global__ __launch_bounds__(256) void scatter_kernel(const int* __restrict__ src,
                                                      const int* __restrict__ dst,
                                                      const int* __restrict__ row_start,
                                                      int* __restrict__ cursor,
                                                      int* __restrict__ esrc,
                                                      int E, int npo) {
    int owner = blockIdx.x & 7;
    int nblk  = gridDim.x >> 3;
    int bo    = blockIdx.x >> 3;
    int lo = owner * npo;
    int hi = lo + npo;
    for (int e = bo * 256 + threadIdx.x; e < E; e += nblk * 256) {
        int d = dst[e];
        if (d >= lo && d < hi) {
            int p = row_start[d] + atomicAdd(&cursor[d], 1);
            esrc[p] = src[e];
        }
    }
}

// ---- GEMM: Hs16[M x 128] = fp16( dinv[m] * (A[M x K] @ W[K x 128]) ) -------
// 64x128 block tile, 256 threads, 4x8 micro-tile. A-tile TRANSPOSED [BK][BM+4]
// so per-kk A-frag = 1 ds_read_b128. Next K-tile is prefetched into registers
// while the current tile computes (T14): HBM latency hides under FMA phase.

__global__ __launch_bounds__(256) void gemm_kernel(const float* __restrict__ A,
                                                   const float* __restrict__ W,
                                                   const float* __restrict__ dinv,
                                                   __half* __restrict__ Hs,
                                                   int M, int K) {
    constexpr int BM = 64, BN = 128, BK = 32, LDT = BM + 4;  // 68
    __shared__ float sAT[BK * LDT];   // 8.7 KB, transposed A tile
    __shared__ float sW[BK][BN];      // 16 KB
    int t = threadIdx.x;
    int row0 = blockIdx.x * BM;
    int tx = t & 15;   // cols tx*4..+3 and 64+tx*4..+3
    int ty = t >> 4;   // rows ty*4..+3
    float acc[4][8] = {};

    float2 ra[4];
    float4 rw[4];
    int nk = (K + BK - 1) / BK;

    // prologue: load tile 0 into regs
#pragma unroll
    for (int j = 0; j < 4; ++j) {
        int s = t + 256 * j; int r = s >> 4; int c2 = s & 15;
        int gr = row0 + r, gk = c2 * 2;
        float2 v = make_float2(0.f, 0.f);
        if (gr < M) {
            if (gk + 1 < K)  v = *reinterpret_cast<const float2*>(&A[(size_t)gr * K + gk]);
            else if (gk < K) v.x = A[(size_t)gr * K + gk];
        }
        ra[j] = v;
    }
#pragma unroll
    for (int j = 0; j < 4; ++j) {
        int s = t + 256 * j; int r = s >> 5; int c4 = s & 31;
        float4 v = make_float4(0.f, 0.f, 0.f, 0.f);
        if (r < K) v = *reinterpret_cast<const float4*>(&W[(size_t)r * BN + c4 * 4]);
        rw[j] = v;
    }

    for (int kt = 0; kt < nk; ++kt) {
        __syncthreads();   // previous compute done -> LDS reusable
        // write staged regs -> LDS (A transposed)
#pragma unroll
        for (int j = 0; j < 4; ++j) {
            int s = t + 256 * j; int r = s >> 4; int c2 = s & 15;
            sAT[(2 * c2) * LDT + r]     = ra[j].x;
            sAT[(2 * c2 + 1) * LDT + r] = ra[j].y;
        }
#pragma unroll
        for (int j = 0; j < 4; ++j) {
            int s = t + 256 * j; int r = s >> 5; int c4 = s & 31;
            *reinterpret_cast<float4*>(&sW[r][c4 * 4]) = rw[j];
        }
        // issue next tile's global loads (complete during compute below)
        if (kt + 1 < nk) {
            int k0 = (kt + 1) * BK;
#pragma unroll
            for (int j = 0; j < 4; ++j) {
                int s = t + 256 * j; int r = s >> 4; int c2 = s & 15;
                int gr = row0 + r, gk = k0 + c2 * 2;
                float2 v = make_float2(0.f, 0.f);
                if (gr < M) {
                    if (gk + 1 < K)  v = *reinterpret_cast<const float2*>(&A[(size_t)gr * K + gk]);
                    else if (gk < K) v.x = A[(size_t)gr * K + gk];
                }
                ra[j] = v;
            }
#pragma unroll
            for (int j = 0; j < 4; ++j) {
                int s = t + 256 * j; int r = s >> 5; int c4 = s & 31;
                int gk = k0 + r;
                float4 v = make_float4(0.f, 0.f, 0.f, 0.f);
                if (gk < K) v = *reinterpret_cast<const float4*>(&W[(size_t)gk * BN + c4 * 4]);
                rw[j] = v;
            }
        }
        __syncthreads();   // LDS tile ready
#pragma unroll 4
        for (int kk = 0; kk < BK; ++kk) {
            float4 av = *reinterpret_cast<const float4*>(&sAT[kk * LDT + ty * 4]);
            float4 b0 = *reinterpret_cast<const float4*>(&sW[kk][tx * 4]);
            float4 b1 = *reinterpret_cast<const float4*>(&sW[kk][64 + tx * 4]);
            float a[4] = {av.x, av.y, av.z, av.w};
#pragma unroll
            for (int i = 0; i < 4; ++i) {
                acc[i][0] = fmaf(a[i], b0.x, acc[i][0]);
                acc[i][1] = fmaf(a[i], b0.y, acc[i][1]);
                acc[i][2] = fmaf(a[i], b0.z, acc[i][2]);
                acc[i][3] = fmaf(a[i], b0.w, acc[i][3]);
                acc[i][4] = fmaf(a[i], b1.x, acc[i][4]);
                acc[i][5] = fmaf(a[i], b1.y, acc[i][5]);
                acc[i][6] = fmaf(a[i], b1.z, acc[i][6]);
                acc[i][7] = fmaf(a[i], b1.w, acc[i][7]);
            }
        }
    }
#pragma unroll
    for (int i = 0; i < 4; ++i) {
        int gr = row0 + ty * 4 + i;
        if (gr < M) {
            float di = dinv[gr];
            __half2 p0 = __floats2half2_rn(di * acc[i][0], di * acc[i][1]);
            __half2 p1 = __floats2half2_rn(di * acc[i][2], di * acc[i][3]);
            __half2 p2 = __floats2half2_rn(di * acc[i][4], di * acc[i][5]);
            __half2 p3 = __floats2half2_rn(di * acc[i][6], di * acc[i][7]);
            uint2 pk0, pk1;
            pk0.x = *reinterpret_cast<unsigned int*>(&p0);
            pk0.y = *reinterpret_cast<unsigned int*>(&p1);
            pk1.x = *reinterpret_cast<unsigned int*>(&p2);
            pk1.y = *reinterpret_cast<unsigned int*>(&p3);
            *reinterpret_cast<uint2*>(&Hs[(size_t)gr * BN + tx * 4])      = pk0;
            *reinterpret_cast<uint2*>(&Hs[(size_t)gr * BN + 64 + tx * 4]) = pk1;
        }
    }
}

// ---- Aggregation: out[i,f] = relu( dinv[i]*(sum_e Hs[s,f] + Hs[i,f]) + b[f] )
// One WAVE per node; c=lane&31 owns feature quad, h=lane>>5 picks edge parity.
// Phase 1 computes 8 edge indices (shfl under the wave-uniform jj<64 branch:
// jj parity means both halves are on the same side of 64 -> all source lanes
// active -> defined ds_bpermute). Phase 2 issues 8 independent gathers.

__global__ __launch_bounds__(256) void agg_kernel(const __half* __restrict__ Hs,
                                                  const int* __restrict__ row_start,
                                                  const int* __restrict__ esrc,
                                                  const float* __restrict__ dinv,
                                                  const float* __restrict__ bias,
                                                  float* __restrict__ out, int N) {
    constexpr int F = 128;
    int node = blockIdx.x * 4 + (threadIdx.x >> 6);
    if (node >= N) return;
    int lane = threadIdx.x & 63;
    int c = lane & 31;
    int h = lane >> 5;
    int beg = row_start[node];
    int deg = row_start[node + 1] - beg;

    int spre = (lane < deg) ? esrc[beg + lane] : 0;  // first 64 edges in regs

    float a0 = 0.f, a1 = 0.f, a2 = 0.f, a3 = 0.f;
    for (int j0 = 0; j0 < deg; j0 += 16) {
        int  sv[8];
        bool ok[8];
#pragma unroll
        for (int u = 0; u < 8; ++u) {
            int jj = j0 + 2 * u + h;
            ok[u] = (jj < deg);
            if (jj < 64) sv[u] = __shfl(spre, jj);       // uniform cond: all lanes active
            else         sv[u] = ok[u] ? esrc[beg + jj] : 0;
        }
        uint2 v[8];
#pragma unroll
        for (int u = 0; u < 8; ++u) {
            v[u] = make_uint2(0u, 0u);
            if (ok[u])
                v[u] = *reinterpret_cast<const uint2*>(&Hs[(size_t)sv[u] * F + c * 4]);
        }
#pragma unroll
        for (int u = 0; u < 8; ++u) {
            __half2 h0 = *reinterpret_cast<__half2*>(&v[u].x);
            __half2 h1 = *reinterpret_cast<__half2*>(&v[u].y);
            float2 f0 = __half22float2(h0);
            float2 f1 = __half22float2(h1);
            a0 += f0.x; a1 += f0.y; a2 += f1.x; a3 += f1.y;
        }
    }
    // combine the two edge-halves
    a0 += __shfl_xor(a0, 32);
    a1 += __shfl_xor(a1, 32);
    a2 += __shfl_xor(a2, 32);
    a3 += __shfl_xor(a3, 32);

    if (h == 0) {
        uint2 sv2 = *reinterpret_cast<const uint2*>(&Hs[(size_t)node * F + c * 4]);
        __half2 s0 = *reinterpret_cast<__half2*>(&sv2.x);
        __half2 s1 = *reinterpret_cast<__half2*>(&sv2.y);
        float2 g0 = __half22float2(s0);
        float2 g1 = __half22float2(s1);
        float4 b = *reinterpret_cast<const float4*>(&bias[c * 4]);
        float di = dinv[node];
        float4 r;
        r.x = fmaxf(fmaf(di, a0 + g0.x, b.x), 0.f);
        r.y = fmaxf(fmaf(di, a1 + g0.y, b.y), 0.f);
        r.z = fmaxf(fmaf(di, a2 + g1.x, b.z), 0.f);
        r.w = fmaxf(fmaf(di, a3 + g1.y, b.w), 0.f);
        *reinterpret_cast<float4*>(&out[(size_t)node * F + c * 4]) = r;
    }
}

// ---- launch ----------------------------------------------------------------

extern "C" void kernel_launch(void* const* d_in, const int* in_sizes, int n_in,
                              void* d_out, int out_size, void* d_ws, size_t ws_size,
                              hipStream_t stream) {
    const float* x  = (const float*)d_in[0];
    const int*   ei = (const int*)d_in[1];     // int32 per harness staging
    const float* W1 = (const float*)d_in[2];
    const float* b1 = (const float*)d_in[3];
    const float* W2 = (const float*)d_in[4];
    const float* b2 = (const float*)d_in[5];

    const int N   = NNODES;
    const int E   = in_sizes[1] / 2;       // 800000
    const int K1  = in_sizes[0] / N;       // 130
    const int HID = in_sizes[3];           // 128
    const int NB  = (N + 255) / 256;       // scan blocks (196)
    const int NPO = (N + 7) / 8;           // nodes per scatter owner (6250)

    const int* src = ei;
    const int* dst = ei + E;

    // workspace layout (all 16B-aligned by construction)
    int*    cnt       = (int*)d_ws;              // N
    int*    cursor    = cnt + N;                 // N
    int*    row_start = cursor + N;              // N+1 (padded to N+4)
    float*  dinv      = (float*)(row_start + N + 4);
    int*    bsum      = (int*)(dinv + N);        // NB (pad 256)
    int*    boff      = bsum + 256;              // NB (pad 256)
    int*    esrc      = boff + 256;              // E
    __half* Hs        = (__half*)(esrc + E);     // N*HID halves (12.8 MB)
    float*  outf      = (float*)d_out;           // N*HID fp32 (also intermediate)

    hipMemsetAsync(cnt, 0, sizeof(int) * 2 * (size_t)N, stream);  // cnt + cursor

    count_kernel<<<(E + 255) / 256, 256, 0, stream>>>(dst, cnt, E);
    scan_blocksum<<<NB, 256, 0, stream>>>(cnt, bsum, N);
    scan_partials<<<1, 256, 0, stream>>>(bsum, boff, row_start, NB, N);
    scan_final<<<NB, 256, 0, stream>>>(cnt, boff, row_start, dinv, N);
    scatter_kernel<<<2048, 256, 0, stream>>>(src, dst, row_start, cursor, esrc, E, NPO);

    // layer 1: gemm -> Hs (fp16 prescaled), agg -> d_out
    gemm_kernel<<<(N + 63) / 64, 256, 0, stream>>>(x, W1, dinv, Hs, N, K1);
    agg_kernel<<<(N + 3) / 4, 256, 0, stream>>>(Hs, row_start, esrc, dinv, b1, outf, N);
    // layer 2: gemm(d_out) -> Hs, agg -> d_out
    gemm_kernel<<<(N + 63) / 64, 256, 0, stream>>>(outf, W2, dinv, Hs, N, HID);
    agg_kernel<<<(N + 3) / 4, 256, 0, stream>>>(Hs, row_start, esrc, dinv, b2, outf, N);
}

// Round 13
// 286.502 us; speedup vs baseline: 1.8250x; 1.0748x over previous
//
#include <hip/hip_runtime.h>
#include <hip/hip_fp16.h>

// GCN 2-layer forward on MI355X.
// Pipeline per call (all on `stream`, graph-capture safe):
//   memset(cnt,cursor) -> count(dst) -> 3-kernel decoupled scan (+dinv)
//   -> scatter(CSR by dst, XCD-partitioned)
//   -> gemm(x,W1)->Hs16 (fp16 MFMA, dinv-prescaled) -> agg+bias+relu -> d_out
//   -> gemm(d_out,W2)->Hs16 -> agg+bias+relu -> d_out
// NOTE: harness stages integer inputs as int32 -> edge_index is const int*.
// R4: parallel 3-kernel scan. R5: fp32 tiled GEMM. R6/7: fp16 prescaled table.
// R8: scatter XCD-partitioned. R9/R10/R11: agg 1 wave/node + batched gathers.
// R12 post-mortem: fp32 GEMM is LDS-throughput-bound (1.33 FLOP/LDS-byte,
//     VALUBusy capped ~33%). R12->R13: GEMM rewritten on the MATRIX pipe:
//     mfma_f32_16x16x32_f16, fp32 accum. W^T resident in LDS fp16 (staged
//     once/block); A-tile fp16 staged per K-tile via ds_write_b128. k-mapping
//     errors cancel (A,B share the mapping); C/D mapping is m89-verified.

#define NNODES 50000

typedef _Float16 f16x8 __attribute__((ext_vector_type(8)));
typedef float    f32x4 __attribute__((ext_vector_type(4)));

// ---- CSR build -------------------------------------------------------------

__global__ void count_kernel(const int* __restrict__ dst, int* __restrict__ cnt, int E) {
    int e = blockIdx.x * blockDim.x + threadIdx.x;
    if (e < E) atomicAdd(&cnt[dst[e]], 1);
}

__global__ __launch_bounds__(256) void scan_blocksum(const int* __restrict__ cnt,
                                                     int* __restrict__ bsum, int N) {
    __shared__ int ws[4];
    int i = blockIdx.x * 256 + threadIdx.x;
    int v = (i < N) ? cnt[i] : 0;
#pragma unroll
    for (int off = 1; off < 64; off <<= 1) v += __shfl_xor(v, off);
    int lane = threadIdx.x & 63, w = threadIdx.x >> 6;
    if (lane == 0) ws[w] = v;
    __syncthreads();
    if (threadIdx.x == 0) bsum[blockIdx.x] = ws[0] + ws[1] + ws[2] + ws[3];
}

__global__ __launch_bounds__(256) void scan_partials(const int* __restrict__ bsum,
                                                     int* __restrict__ boff,
                                                     int* __restrict__ row_start,
                                                     int NB, int N) {
    __shared__ int ws[4];
    int t = threadIdx.x;
    int v = (t < NB) ? bsum[t] : 0;
    int lane = t & 63, w = t >> 6;
    int inc = v;
#pragma unroll
    for (int off = 1; off < 64; off <<= 1) {
        int n = __shfl_up(inc, off);
        if (lane >= off) inc += n;
    }
    if (lane == 63) ws[w] = inc;
    __syncthreads();
    int woff = 0;
    for (int k = 0; k < w; ++k) woff += ws[k];
    int excl = woff + inc - v;
    if (t < NB) boff[t] = excl;
    if (t == NB - 1) row_start[N] = excl + v;  // grand total = E
}

__global__ __launch_bounds__(256) void scan_final(const int* __restrict__ cnt,
                                                  const int* __restrict__ boff,
                                                  int* __restrict__ row_start,
                                                  float* __restrict__ dinv, int N) {
    __shared__ int ws[4];
    int i = blockIdx.x * 256 + threadIdx.x;
    int v = (i < N) ? cnt[i] : 0;
    int lane = threadIdx.x & 63, w = threadIdx.x >> 6;
    int inc = v;
#pragma unroll
    for (int off = 1; off < 64; off <<= 1) {
        int n = __shfl_up(inc, off);
        if (lane >= off) inc += n;
    }
    if (lane == 63) ws[w] = inc;
    __syncthreads();
    int woff = 0;
    for (int k = 0; k < w; ++k) woff += ws[k];
    if (i < N) {
        row_start[i] = boff[blockIdx.x] + woff + inc - v;
        dinv[i] = rsqrtf((float)(v + 1));  // +1 self-loop; deg>=1 always
    }
}

__global__ __launch_bounds__(256) void scatter_kernel(const int* __restrict__ src,
                                                      const int* __restrict__ dst,
                                                      const int* __restrict__ row_start,
                                                      int* __restrict__ cursor,
                                                      int* __restrict__ esrc,
                                                      int E, int npo) {
    int owner = blockIdx.x & 7;
    int nblk  = gridDim.x >> 3;
    int bo    = blockIdx.x >> 3;
    int lo = owner * npo;
    int hi = lo + npo;
    for (int e = bo * 256 + threadIdx.x; e < E; e += nblk * 256) {
        int d = dst[e];
        if (d >= lo && d < hi) {
            int p = row_start[d] + atomicAdd(&cursor[d], 1);
            esrc[p] = src[e];
        }
    }
}

// ---- MFMA GEMM: Hs16[M x 128] = fp16( dinv[m] * (A[M x K] @ W[K x 128]) ) --
// 256 threads = 4 waves; tile 64x128; wave w owns rows [w*16,w*16+16) x all
// 8 col-frags. mfma_f32_16x16x32_f16: A-frag row=lane&15, k=(lane>>4)*8+i;
// B-frag col=lane&15, same k-map; D col=lane&15, row=(lane>>4)*4+reg (m89).
// W^T in LDS fp16 [128][LDK=168] staged once; A fp16 [64][40] per K-tile.

__global__ __launch_bounds__(256) void gemm_kernel(const float* __restrict__ A,
                                                   const float* __restrict__ W,
                                                   const float* __restrict__ dinv,
                                                   __half* __restrict__ Hs,
                                                   int M, int K) {
    constexpr int BM = 64, BN = 128, BK = 32;
    constexpr int LDA = 40;    // halves; 80B row = 16B-aligned, 2-way bank alias
    constexpr int LDK = 168;   // halves; 336B row = 16B-aligned, 2-way bank alias
    __shared__ _Float16 sA[BM * LDA];   // 5.1 KB
    __shared__ _Float16 sB[BN * LDK];   // 43  KB  (W transposed: [n][k])
    int t = threadIdx.x;
    int lane = t & 63;
    int wv   = t >> 6;                  // wave id -> row-group
    int row0 = blockIdx.x * BM;
    int nk = (K + BK - 1) / BK;

    // ---- stage W^T once: sB[n][k] = fp16(W[k][n]); zero-pad k in [K, nk*32)
    {
        int n = t & 127;
        for (int kb = (t >> 7); kb < K; kb += 2)
            sB[n * LDK + kb] = (_Float16)W[(size_t)kb * BN + n];
        for (int kb = K + (t >> 7); kb < nk * BK; kb += 2)
            sB[n * LDK + kb] = (_Float16)0.f;
    }

    f32x4 acc[8] = {};
    int ar = t >> 2;               // A-stage row 0..63
    int ac = (t & 3) * 8;          // A-stage k-offset {0,8,16,24}

    for (int kt = 0; kt < nk; ++kt) {
        int k0 = kt * BK;
        __syncthreads();           // prev compute done (and, at kt=0, nothing)
        // stage A: 8 k's per thread as float2 pairs -> one ds_write_b128
        {
            int gr = row0 + ar;
            f16x8 hv;
#pragma unroll
            for (int j = 0; j < 4; ++j) {
                int gk = k0 + ac + 2 * j;
                float2 v = make_float2(0.f, 0.f);
                if (gr < M) {
                    if (gk + 1 < K)  v = *reinterpret_cast<const float2*>(&A[(size_t)gr * K + gk]);
                    else if (gk < K) v.x = A[(size_t)gr * K + gk];
                }
                hv[2 * j]     = (_Float16)v.x;
                hv[2 * j + 1] = (_Float16)v.y;
            }
            *reinterpret_cast<f16x8*>(&sA[ar * LDA + ac]) = hv;
        }
        __syncthreads();           // A tile (and W at kt=0) visible
        // compute: 1 A-frag, 8 B-frags, 8 mfma
        f16x8 af = *reinterpret_cast<const f16x8*>(
            &sA[(wv * 16 + (lane & 15)) * LDA + (lane >> 4) * 8]);
#pragma unroll
        for (int nf = 0; nf < 8; ++nf) {
            f16x8 bf = *reinterpret_cast<const f16x8*>(
                &sB[(nf * 16 + (lane & 15)) * LDK + k0 + (lane >> 4) * 8]);
            acc[nf] = __builtin_amdgcn_mfma_f32_16x16x32_f16(af, bf, acc[nf], 0, 0, 0);
        }
    }

    // ---- epilogue: D col = lane&15, row = (lane>>4)*4 + r  (m89-verified)
    int ccol  = lane & 15;
    int rbase = row0 + wv * 16 + (lane >> 4) * 4;
#pragma unroll
    for (int r = 0; r < 4; ++r) {
        int gr = rbase + r;
        if (gr < M) {
            float di = dinv[gr];
#pragma unroll
            for (int nf = 0; nf < 8; ++nf)
                Hs[(size_t)gr * BN + nf * 16 + ccol] = __float2half(di * acc[nf][r]);
        }
    }
}

// ---- Aggregation: out[i,f] = relu( dinv[i]*(sum_e Hs[s,f] + Hs[i,f]) + b[f] )
// One WAVE per node; c=lane&31 owns feature quad, h=lane>>5 picks edge parity.
// Shfl under the wave-uniform jj<64 branch (all source lanes active: defined).
// 8 independent gathers per batch (16 edges in flight) hide LLC latency.

__global__ __launch_bounds__(256) void agg_kernel(const __half* __restrict__ Hs,
                                                  const int* __restrict__ row_start,
                                                  const int* __restrict__ esrc,
                                                  const float* __restrict__ dinv,
                                                  const float* __restrict__ bias,
                                                  float* __restrict__ out, int N) {
    constexpr int F = 128;
    int node = blockIdx.x * 4 + (threadIdx.x >> 6);
    if (node >= N) return;
    int lane = threadIdx.x & 63;
    int c = lane & 31;
    int h = lane >> 5;
    int beg = row_start[node];
    int deg = row_start[node + 1] - beg;

    int spre = (lane < deg) ? esrc[beg + lane] : 0;  // first 64 edges in regs

    float a0 = 0.f, a1 = 0.f, a2 = 0.f, a3 = 0.f;
    for (int j0 = 0; j0 < deg; j0 += 16) {
        int  sv[8];
        bool ok[8];
#pragma unroll
        for (int u = 0; u < 8; ++u) {
            int jj = j0 + 2 * u + h;
            ok[u] = (jj < deg);
            if (jj < 64) sv[u] = __shfl(spre, jj);       // uniform cond: all lanes active
            else         sv[u] = ok[u] ? esrc[beg + jj] : 0;
        }
        uint2 v[8];
#pragma unroll
        for (int u = 0; u < 8; ++u) {
            v[u] = make_uint2(0u, 0u);
            if (ok[u])
                v[u] = *reinterpret_cast<const uint2*>(&Hs[(size_t)sv[u] * F + c * 4]);
        }
#pragma unroll
        for (int u = 0; u < 8; ++u) {
            __half2 h0 = *reinterpret_cast<__half2*>(&v[u].x);
            __half2 h1 = *reinterpret_cast<__half2*>(&v[u].y);
            float2 f0 = __half22float2(h0);
            float2 f1 = __half22float2(h1);
            a0 += f0.x; a1 += f0.y; a2 += f1.x; a3 += f1.y;
        }
    }
    a0 += __shfl_xor(a0, 32);
    a1 += __shfl_xor(a1, 32);
    a2 += __shfl_xor(a2, 32);
    a3 += __shfl_xor(a3, 32);

    if (h == 0) {
        uint2 sv2 = *reinterpret_cast<const uint2*>(&Hs[(size_t)node * F + c * 4]);
        __half2 s0 = *reinterpret_cast<__half2*>(&sv2.x);
        __half2 s1 = *reinterpret_cast<__half2*>(&sv2.y);
        float2 g0 = __half22float2(s0);
        float2 g1 = __half22float2(s1);
        float4 b = *reinterpret_cast<const float4*>(&bias[c * 4]);
        float di = dinv[node];
        float4 r;
        r.x = fmaxf(fmaf(di, a0 + g0.x, b.x), 0.f);
        r.y = fmaxf(fmaf(di, a1 + g0.y, b.y), 0.f);
        r.z = fmaxf(fmaf(di, a2 + g1.x, b.z), 0.f);
        r.w = fmaxf(fmaf(di, a3 + g1.y, b.w), 0.f);
        *reinterpret_cast<float4*>(&out[(size_t)node * F + c * 4]) = r;
    }
}

// ---- launch ----------------------------------------------------------------

extern "C" void kernel_launch(void* const* d_in, const int* in_sizes, int n_in,
                              void* d_out, int out_size, void* d_ws, size_t ws_size,
                              hipStream_t stream) {
    const float* x  = (const float*)d_in[0];
    const int*   ei = (const int*)d_in[1];     // int32 per harness staging
    const float* W1 = (const float*)d_in[2];
    const float* b1 = (const float*)d_in[3];
    const float* W2 = (const float*)d_in[4];
    const float* b2 = (const float*)d_in[5];

    const int N   = NNODES;
    const int E   = in_sizes[1] / 2;       // 800000
    const int K1  = in_sizes[0] / N;       // 130
    const int HID = in_sizes[3];           // 128
    const int NB  = (N + 255) / 256;       // scan blocks (196)
    const int NPO = (N + 7) / 8;           // nodes per scatter owner (6250)

    const int* src = ei;
    const int* dst = ei + E;

    // workspace layout (all 16B-aligned by construction)
    int*    cnt       = (int*)d_ws;              // N
    int*    cursor    = cnt + N;                 // N
    int*    row_start = cursor + N;              // N+1 (padded to N+4)
    float*  dinv      = (float*)(row_start + N + 4);
    int*    bsum      = (int*)(dinv + N);        // NB (pad 256)
    int*    boff      = bsum + 256;              // NB (pad 256)
    int*    esrc      = boff + 256;              // E
    __half* Hs        = (__half*)(esrc + E);     // N*HID halves (12.8 MB)
    float*  outf      = (float*)d_out;           // N*HID fp32 (also intermediate)

    hipMemsetAsync(cnt, 0, sizeof(int) * 2 * (size_t)N, stream);  // cnt + cursor

    count_kernel<<<(E + 255) / 256, 256, 0, stream>>>(dst, cnt, E);
    scan_blocksum<<<NB, 256, 0, stream>>>(cnt, bsum, N);
    scan_partials<<<1, 256, 0, stream>>>(bsum, boff, row_start, NB, N);
    scan_final<<<NB, 256, 0, stream>>>(cnt, boff, row_start, dinv, N);
    scatter_kernel<<<2048, 256, 0, stream>>>(src, dst, row_start, cursor, esrc, E, NPO);

    // layer 1: mfma gemm -> Hs (fp16 prescaled), agg -> d_out
    gemm_kernel<<<(N + 63) / 64, 256, 0, stream>>>(x, W1, dinv, Hs, N, K1);
    agg_kernel<<<(N + 3) / 4, 256, 0, stream>>>(Hs, row_start, esrc, dinv, b1, outf, N);
    // layer 2: mfma gemm(d_out) -> Hs, agg -> d_out
    gemm_kernel<<<(N + 63) / 64, 256, 0, stream>>>(outf, W2, dinv, Hs, N, HID);
    agg_kernel<<<(N + 3) / 4, 256, 0, stream>>>(Hs, row_start, esrc, dinv, b2, outf, N);
}